// Round 10
// baseline (545.429 us; speedup 1.0000x reference)
//
#include <hip/hip_runtime.h>
#include <hip/hip_bf16.h>

typedef __attribute__((ext_vector_type(8))) __bf16 bf16x8;
typedef __attribute__((ext_vector_type(4))) float f32x4;
typedef unsigned short ushort_t;

#define Bdim 64
#define Tdim 32
#define Edim 512
#define Fdim 512
#define Hdim 1024
#define Vdim 10000
#define SCAN_BLOCKS 256

__device__ __forceinline__ float bf2f(ushort_t u) {
    unsigned int x = ((unsigned int)u) << 16;
    union { unsigned int i; float f; } c; c.i = x; return c.f;
}
__device__ __forceinline__ ushort_t f2bf(float f) {
    __hip_bfloat16 h = __float2bfloat16(f);
    union { __hip_bfloat16 h; ushort_t u; } c; c.h = h; return c.u;
}

__device__ __forceinline__ void gload_lds16(const void* g, void* l) {
    __builtin_amdgcn_global_load_lds(
        (const __attribute__((address_space(1))) unsigned int*)g,
        (__attribute__((address_space(3))) unsigned int*)l, 16, 0, 0);
}

// write-through stores: visible device-wide once vmcnt-complete, no dirty local-L2 line
__device__ __forceinline__ void store_short_wt(ushort_t* p, ushort_t v) {
    asm volatile("global_store_short %0, %1, off sc0 sc1"
                 : : "v"(p), "v"((unsigned int)v) : "memory");
}
__device__ __forceinline__ void store_byte_wt(unsigned char* p, unsigned int v) {
    asm volatile("global_store_byte %0, %1, off sc0 sc1"
                 : : "v"(p), "v"(v) : "memory");
}

// ---------------- Stage 0: f32 -> bf16 mirror of weights + h0; zero flags ----------------
__global__ void cvt_all(const float* __restrict__ vw, const float* __restrict__ sw,
                        const float* __restrict__ uw, const float* __restrict__ ww,
                        const float* __restrict__ cw, const float* __restrict__ h0,
                        ushort_t* __restrict__ mir, unsigned int* __restrict__ flg) {
    if (blockIdx.x == 0) {   // zero flags: 32 steps x 256 byte-flags = 8 KiB
        int4 zz = {0, 0, 0, 0};
        ((int4*)flg)[threadIdx.x * 2 + 0] = zz;
        ((int4*)flg)[threadIdx.x * 2 + 1] = zz;
    }
    long idx = ((long)blockIdx.x * blockDim.x + threadIdx.x) * 8;
    const float* src; long off;
    if      (idx <  1048576L) { src = vw; off = idx; }
    else if (idx <  2097152L) { src = sw; off = idx - 1048576L; }
    else if (idx <  4194304L) { src = uw; off = idx - 2097152L; }
    else if (idx <  8388608L) { src = ww; off = idx - 4194304L; }
    else if (idx < 18628608L) { src = cw; off = idx - 8388608L; }
    else if (idx < 18694144L) { src = h0; off = idx - 18628608L; }
    else return;
    float4 a = *(const float4*)(src + off);
    float4 b = *(const float4*)(src + off + 4);
    ushort_t o[8];
    o[0] = f2bf(a.x); o[1] = f2bf(a.y); o[2] = f2bf(a.z); o[3] = f2bf(a.w);
    o[4] = f2bf(b.x); o[5] = f2bf(b.y); o[6] = f2bf(b.z); o[7] = f2bf(b.w);
    *(int4*)(mir + idx) = *(const int4*)o;
}

// ---------------- Stage A: x = [img ; B_emb[captions[:, :-1]]], f32 -> bf16 ----------------
__global__ void build_x(const int* __restrict__ cap,
                        const float* __restrict__ img,
                        const float* __restrict__ emb,
                        ushort_t* __restrict__ X) {
    int idx = blockIdx.x * blockDim.x + threadIdx.x;
    int row = idx >> 6;
    int c8  = (idx & 63) << 3;
    int b = row >> 5, t = row & 31;
    const float* src = (t == 0) ? (img + (size_t)b * Edim)
                                : (emb + (size_t)cap[b * Tdim + (t - 1)] * Edim);
    float4 a  = *(const float4*)(src + c8);
    float4 bb = *(const float4*)(src + c8 + 4);
    ushort_t o[8];
    o[0] = f2bf(a.x);  o[1] = f2bf(a.y);  o[2] = f2bf(a.z);  o[3] = f2bf(a.w);
    o[4] = f2bf(bb.x); o[5] = f2bf(bb.y); o[6] = f2bf(bb.z); o[7] = f2bf(bb.w);
    *(int4*)(X + (size_t)row * Edim + c8) = *(const int4*)o;
}

// ---------------- Generic GEMM: C[m][n] = sum_k A[m][k]*Bt[n][k] + bias[n] ----------------
// T2 LDS XOR-swizzle; T1 XCD remap; zpack: [t][cg256][wrow16][b64] layout for lstm_scan
// (wrow = gate*4 + (col&3), cg = col>>2). aswap=1: logical A-row (b*32+t) stored at (t*64+b).
__launch_bounds__(256)
__global__ void gemm_bt(const ushort_t* __restrict__ A, long lda, long gsA,
                        const ushort_t* __restrict__ Bm, long ldb, long gsB,
                        void* __restrict__ Cv, long ldc, long gsC,
                        const float* __restrict__ bias, long gsBias,
                        int N, int K, int f32out, int zpack, int aswap) {
    __shared__ ushort_t As[128 * 64];
    __shared__ ushort_t Bs[128 * 64];
    int z = blockIdx.z;
    A += (size_t)z * gsA; Bm += (size_t)z * gsB; bias += (size_t)z * gsBias;

    // T1: XCD-aware remap (per-z slab; slab sizes here are all %8==0)
    int nx = gridDim.x, ny = gridDim.y;
    int lin = blockIdx.x + nx * blockIdx.y;
    int per_xcd = (nx * ny) >> 3;
    int l2 = (lin & 7) * per_xcd + (lin >> 3);
    int bx = l2 / ny, by = l2 % ny;

    int tid = threadIdx.x;
    int w = tid >> 6, l = tid & 63;
    int wm = (w >> 1) * 64, wn = (w & 1) * 64;
    int m0 = by * 128, n0 = bx * 128;

    int srow = tid >> 3;
    int scol = (tid & 7) << 3;

    int lane_r = l & 15;
    int lane_k = (l >> 4) << 3;

    f32x4 zero = {0.f, 0.f, 0.f, 0.f};
    f32x4 acc[4][4];
#pragma unroll
    for (int i = 0; i < 4; i++)
#pragma unroll
        for (int j = 0; j < 4; j++) acc[i][j] = zero;

    for (int k0 = 0; k0 < K; k0 += 64) {
#pragma unroll
        for (int j = 0; j < 4; j++) {
            int r = srow + j * 32;
            int pr = m0 + r;
            if (aswap) pr = ((pr & 31) << 6) + (pr >> 5);
            int sc = scol ^ ((r & 7) << 3);
            gload_lds16(A + (size_t)pr * lda + k0 + sc, &As[r * 64 + scol]);
        }
#pragma unroll
        for (int j = 0; j < 4; j++) {
            int r = srow + j * 32;
            int br = n0 + r; if (br > N - 1) br = N - 1;
            int sc = scol ^ ((r & 7) << 3);
            gload_lds16(Bm + (size_t)br * ldb + k0 + sc, &Bs[r * 64 + scol]);
        }
        __syncthreads();
#pragma unroll
        for (int kk = 0; kk < 64; kk += 32) {
            bf16x8 af[4], bfr[4];
#pragma unroll
            for (int i = 0; i < 4; i++) {
                int ar = wm + i * 16 + lane_r;
                af[i] = *(const bf16x8*)&As[ar * 64 + ((kk + lane_k) ^ ((ar & 7) << 3))];
            }
#pragma unroll
            for (int j = 0; j < 4; j++) {
                int br2 = wn + j * 16 + lane_r;
                bfr[j] = *(const bf16x8*)&Bs[br2 * 64 + ((kk + lane_k) ^ ((br2 & 7) << 3))];
            }
#pragma unroll
            for (int i = 0; i < 4; i++)
#pragma unroll
                for (int j = 0; j < 4; j++)
                    acc[i][j] = __builtin_amdgcn_mfma_f32_16x16x32_bf16(af[i], bfr[j], acc[i][j], 0, 0, 0);
        }
        __syncthreads();
    }

    int row_base = m0 + wm + ((l >> 4) << 2);
    int col_base = n0 + wn + lane_r;
#pragma unroll
    for (int j = 0; j < 4; j++) {
        int col = col_base + j * 16;
        if (col < N) {
            float bv = bias[col];
#pragma unroll
            for (int i = 0; i < 4; i++) {
#pragma unroll
                for (int r = 0; r < 4; r++) {
                    int row = row_base + i * 16 + r;
                    float v = acc[i][j][r] + bv;
                    if (zpack) {
                        int b = row >> 5, tt = row & 31;
                        size_t idx = (((size_t)(tt * 256 + (col >> 2)) * 16)
                                      + (size_t)(z * 4 + (col & 3))) * 64 + b;
                        ((ushort_t*)Cv)[idx] = f2bf(v);
                    } else if (f32out) {
                        ((float*)Cv)[(size_t)z * gsC + (size_t)row * ldc + col] = v;
                    } else {
                        ((ushort_t*)Cv)[(size_t)z * gsC + (size_t)row * ldc + col] = f2bf(v);
                    }
                }
            }
        }
    }
}

// hand-issued 16B load with literal offset into ring slot i (compiler cannot serialize)
#define GLD(i, o) asm volatile("global_load_dwordx4 %0, %1, off offset:" o \
                               : "=v"(ab[i]) : "v"(apx))
// One k-chunk: ds_read for chunk d+1 BEFORE the counted wait (its lgkmcnt is satisfied
// during chunk d -> no LDS stall); sched_barrier(0) is the only verified MFMA fence
// (rule #18). ISSUE refills the global ring slot.
#define CHUNK(d, n, ISSUE)                                                                   \
    do {                                                                                     \
        const int kc2n = (((d) + 1) * 32 + lane_kb) * 2;                                     \
        bf16x8 bnx = *(const bf16x8*)((const char*)Ws + (wrow_b * 2048 + (kc2n ^ swz)));     \
        asm volatile("s_waitcnt vmcnt(" n ")");                                              \
        __builtin_amdgcn_sched_barrier(0);                                                   \
        bf16x8 av = __builtin_bit_cast(bf16x8, ab[(d) & 15]);                                \
        acc = __builtin_amdgcn_mfma_f32_16x16x32_bf16(av, bcur, acc, 0, 0, 0);               \
        ISSUE;                                                                               \
        bcur = bnx;                                                                          \
    } while (0)
#define CHUNKL(d, n)                                                                         \
    do {                                                                                     \
        asm volatile("s_waitcnt vmcnt(" n ")");                                              \
        __builtin_amdgcn_sched_barrier(0);                                                   \
        bf16x8 av = __builtin_bit_cast(bf16x8, ab[(d) & 15]);                                \
        acc = __builtin_amdgcn_mfma_f32_16x16x32_bf16(av, bcur, acc, 0, 0, 0);               \
    } while (0)

// ---------------- Stage E: persistent LSTM scan, 256 blocks (all CUs) ----------------
// Block cg owns 4 hcols x 4 gates (16 W-rows, 32 KiB LDS). 4 waves x 16 batch rows.
// Lane owns one wrow = gate*4+hcol (l&15); 4-gate gather via width-16 shuffles.
// h handoff: WT stores + per-producer byte flags (poll = 1 dword load + ballot).
__launch_bounds__(256, 1)
__global__ void lstm_scan(const ushort_t* __restrict__ Wm,   // bf16 [4*1024][1024]
                          const float* __restrict__ Wb,      // f32 [4][1024]
                          const ushort_t* __restrict__ zb,   // packed g3 [t][cg][wrow][b]
                          const ushort_t* __restrict__ h0b,  // bf16 [64][1024]
                          const float* __restrict__ c0,      // f32 [64][1024]
                          ushort_t* __restrict__ Hbt,        // bf16 [t][64][1024]
                          unsigned int* __restrict__ flags) { // [32][64] dwords = [32][256] bytes
    __shared__ ushort_t Ws[16 * 1024];   // 32 KiB
    int cg = blockIdx.x;
    int tid = threadIdx.x;
    int w = tid >> 6, l = tid & 63;
    int lane_r = l & 15, lane_kb = (l >> 4) << 3;

    // ---- prologue: stage 16 W-rows into LDS with 16B XOR swizzle (reg-staged) ----
    for (int e = tid * 8; e < 16384; e += 2048) {
        int rowl = e >> 10, ke = e & 1023;          // wrow = g*4 + hc
        const ushort_t* src = Wm + ((size_t)((rowl >> 2) * Hdim + cg * 4 + (rowl & 3))) * Hdim + ke;
        int dstb = rowl * 2048 + ((ke * 2) ^ ((rowl & 7) << 4));
        *(int4*)((char*)Ws + dstb) = *(const int4*)src;
    }
    int hc = l & 3;                                  // this lane's output hcol (in-block)
    int hcol = cg * 4 + hc;                          // global h column
    float wbv = Wb[(lane_r >> 2) * Hdim + hcol - hc + (lane_r & 3)];  // own wrow bias
    int rb0 = w * 16 + ((l >> 4) << 2);              // first of this thread's 4 batch rows
    float cst[4];
#pragma unroll
    for (int r = 0; r < 4; r++) cst[r] = c0[(size_t)(rb0 + r) * Hdim + hcol];
    __syncthreads();

    int arow = w * 16 + lane_r;
    int swz = (l & 7) << 4;
    int wrow_b = lane_r;                              // B-frag row for this lane

    for (int t = 0; t < Tdim; t++) {
        // g3 for own wrow, 4 batch rows (8B) — issue before the poll
        ushort4 g3v = *(const ushort4*)(zb + (((size_t)t * 256 + cg) * 16 + lane_r) * 64 + rb0);

        // wait for ALL step-(t-1) producers: lane l watches 4 packed byte-flags
        if (t > 0) {
            const unsigned int* fp = flags + (size_t)(t - 1) * 64 + l;
            unsigned int v;
            do {
                v = __hip_atomic_load(fp, __ATOMIC_RELAXED, __HIP_MEMORY_SCOPE_AGENT);
            } while (__ballot(v == 0x01010101u) != 0xFFFFFFFFFFFFFFFFull);
        }
        __builtin_amdgcn_sched_barrier(0);   // nothing crosses the poll

        const ushort_t* hp = t ? (Hbt + (size_t)(t - 1) * (Bdim * Hdim)) : h0b;
        const ushort_t* apx = hp + (size_t)arow * Hdim + lane_kb;

        // prime the 16-deep global ring (chunks 0..15; 64B apart)
        int4 ab[16];
        GLD(0, "0");    GLD(1, "64");   GLD(2, "128");  GLD(3, "192");
        GLD(4, "256");  GLD(5, "320");  GLD(6, "384");  GLD(7, "448");
        GLD(8, "512");  GLD(9, "576");  GLD(10, "640"); GLD(11, "704");
        GLD(12, "768"); GLD(13, "832"); GLD(14, "896"); GLD(15, "960");

        f32x4 acc = {0.f, 0.f, 0.f, 0.f};
        bf16x8 bcur = *(const bf16x8*)((const char*)Ws + (wrow_b * 2048 + ((lane_kb * 2) ^ swz)));

        CHUNK(0, "15", GLD(0, "1024"));   CHUNK(1, "15", GLD(1, "1088"));
        CHUNK(2, "15", GLD(2, "1152"));   CHUNK(3, "15", GLD(3, "1216"));
        CHUNK(4, "15", GLD(4, "1280"));   CHUNK(5, "15", GLD(5, "1344"));
        CHUNK(6, "15", GLD(6, "1408"));   CHUNK(7, "15", GLD(7, "1472"));
        CHUNK(8, "15", GLD(8, "1536"));   CHUNK(9, "15", GLD(9, "1600"));
        CHUNK(10, "15", GLD(10, "1664")); CHUNK(11, "15", GLD(11, "1728"));
        CHUNK(12, "15", GLD(12, "1792")); CHUNK(13, "15", GLD(13, "1856"));
        CHUNK(14, "15", GLD(14, "1920")); CHUNK(15, "15", GLD(15, "1984"));
        CHUNK(16, "15", (void)0); CHUNK(17, "14", (void)0);
        CHUNK(18, "13", (void)0); CHUNK(19, "12", (void)0);
        CHUNK(20, "11", (void)0); CHUNK(21, "10", (void)0);
        CHUNK(22, "9", (void)0);  CHUNK(23, "8", (void)0);
        CHUNK(24, "7", (void)0);  CHUNK(25, "6", (void)0);
        CHUNK(26, "5", (void)0);  CHUNK(27, "4", (void)0);
        CHUNK(28, "3", (void)0);  CHUNK(29, "2", (void)0);
        CHUNK(30, "1", (void)0);  CHUNKL(31, "0");

        // epilogue: lane holds z for its wrow (l&15), 4 batch rows. Gather 4 gates
        // for hcol = l&3 via width-16 shuffles; all lanes compute (4x redundant, free);
        // only the gate-0 lane group (l&12 == 0) stores h.
#pragma unroll
        for (int r = 0; r < 4; r++) {
            float zown = acc[r] + wbv + bf2f(g3v[r]);
            float zi = __shfl(zown, hc,      16);
            float zf = __shfl(zown, hc + 4,  16);
            float zo = __shfl(zown, hc + 8,  16);
            float zc = __shfl(zown, hc + 12, 16);
            float it = __builtin_amdgcn_rcpf(1.f + __expf(-zi));
            float ft = __builtin_amdgcn_rcpf(1.f + __expf(-zf));
            float ot = __builtin_amdgcn_rcpf(1.f + __expf(-zo));
            float e2 = __expf(-2.f * zc);
            float ct = (1.f - e2) * __builtin_amdgcn_rcpf(1.f + e2);
            float cn = ft * cst[r] + it * ct;
            cst[r] = cn;
            if ((l & 12) == 0)
                store_short_wt(Hbt + (size_t)t * (Bdim * Hdim) + (size_t)(rb0 + r) * Hdim + hcol,
                               f2bf(ot * cn));
        }

        // drain this wave's h stores, block-arrive, publish own byte flag (plain WT store)
        asm volatile("s_waitcnt vmcnt(0)" ::: "memory");
        __syncthreads();
        if (tid == 0) store_byte_wt((unsigned char*)flags + (size_t)t * 256 + cg, 1u);
    }
}

extern "C" void kernel_launch(void* const* d_in, const int* in_sizes, int n_in,
                              void* d_out, int out_size, void* d_ws, size_t ws_size,
                              hipStream_t stream) {
    const int*   cap  = (const int*)d_in[0];
    const float* img  = (const float*)d_in[1];
    const float* Bemb = (const float*)d_in[2];
    const float* V_W  = (const float*)d_in[3];
    const float* V_b  = (const float*)d_in[4];
    const float* S_W  = (const float*)d_in[5];
    const float* S_b  = (const float*)d_in[6];
    const float* U_W  = (const float*)d_in[7];
    const float* U_b  = (const float*)d_in[8];
    const float* W_W  = (const float*)d_in[9];
    const float* W_b  = (const float*)d_in[10];
    const float* C_W  = (const float*)d_in[11];
    const float* C_b  = (const float*)d_in[12];
    const float* h0   = (const float*)d_in[13];
    const float* c0   = (const float*)d_in[14];

    char* ws = (char*)d_ws;
    ushort_t* mir = (ushort_t*)(ws);                       // 35.7 MiB bf16 mirror
    ushort_t* X   = (ushort_t*)(ws + (size_t)(36u << 20)); // 2 MiB
    ushort_t* g1  = (ushort_t*)(ws + (size_t)(38u << 20)); // 8 MiB
    ushort_t* g2  = (ushort_t*)(ws + (size_t)(46u << 20)); // 8 MiB
    ushort_t* Hbt = (ushort_t*)(ws + (size_t)(54u << 20)); // 4 MiB [t][b][h]
    unsigned int* flags = (unsigned int*)(ws + (size_t)(58u << 20)); // 8 KiB
    ushort_t* zb  = (ushort_t*)d_out;                      // 16 MiB scratch, dead before stage F

    const ushort_t* V_Wb = mir;
    const ushort_t* S_Wb = mir + 1048576L;
    const ushort_t* U_Wb = mir + 2097152L;
    const ushort_t* W_Wb = mir + 4194304L;
    const ushort_t* C_Wb = mir + 8388608L;
    const ushort_t* h0b  = mir + 18628608L;

    cvt_all<<<9128, 256, 0, stream>>>(V_W, S_W, U_W, W_W, C_W, h0, mir, flags);
    build_x<<<512, 256, 0, stream>>>(cap, img, Bemb, X);

    // Stage B: g1 = X (2048x512) * V_Wcat^T (2048x512) + V_b
    gemm_bt<<<dim3(16, 16, 1), 256, 0, stream>>>(X, 512, 0, V_Wb, 512, 0,
                                                 g1, 2048, 0, V_b, 0, 2048, 512, 0, 0, 0);
    // Stage C (per gate): g2[:, g] = g1[:, g] * S_W[g]^T + S_b[g]
    gemm_bt<<<dim3(4, 16, 4), 256, 0, stream>>>(g1, 2048, 512, S_Wb, 512, 512 * 512,
                                                g2, 2048, 512, S_b, 512, 512, 512, 0, 0, 0);
    // Stage D (per gate): zb(packed) = g2[:, g] * U_W[g]^T + U_b[g]
    gemm_bt<<<dim3(8, 16, 4), 256, 0, stream>>>(g2, 2048, 512, U_Wb, 512, 1024 * 512,
                                                zb, 0, 0, U_b, 1024, 1024, 512, 0, 1, 0);
    // Stage E: persistent scan — cooperative launch guarantees co-residency (256 blocks)
    {
        const ushort_t* a0 = W_Wb; const float* a1 = W_b; const ushort_t* a2 = zb;
        const ushort_t* a3 = h0b;  const float* a4 = c0;  ushort_t* a5 = Hbt;
        unsigned int* a6 = flags;
        void* sargs[7] = {(void*)&a0, (void*)&a1, (void*)&a2, (void*)&a3,
                          (void*)&a4, (void*)&a5, (void*)&a6};
        hipLaunchCooperativeKernel((const void*)lstm_scan, dim3(SCAN_BLOCKS), dim3(256),
                                   sargs, 0, stream);
    }
    // Stage F: out = Hbt([t][b][h], aswap) (2048x1024) * C_W^T (10000x1024) + C_b (f32 out)
    gemm_bt<<<dim3(79, 16, 1), 256, 0, stream>>>(Hbt, 1024, 0, C_Wb, 1024, 0,
                                                 d_out, 10000, 0, C_b, 0,
                                                 10000, 1024, 1, 0, 1);
}

// Round 12
// 383.970 us; speedup vs baseline: 1.4205x; 1.4205x over previous
//
#include <hip/hip_runtime.h>
#include <hip/hip_bf16.h>

typedef __attribute__((ext_vector_type(8))) __bf16 bf16x8;
typedef __attribute__((ext_vector_type(4))) float f32x4;
typedef unsigned short ushort_t;

#define Bdim 64
#define Tdim 32
#define Edim 512
#define Fdim 512
#define Hdim 1024
#define Vdim 10000
#define SCAN_BLOCKS 64

__device__ __forceinline__ float bf2f(ushort_t u) {
    unsigned int x = ((unsigned int)u) << 16;
    union { unsigned int i; float f; } c; c.i = x; return c.f;
}
__device__ __forceinline__ ushort_t f2bf(float f) {
    __hip_bfloat16 h = __float2bfloat16(f);
    union { __hip_bfloat16 h; ushort_t u; } c; c.h = h; return c.u;
}

__device__ __forceinline__ void gload_lds16(const void* g, void* l) {
    __builtin_amdgcn_global_load_lds(
        (const __attribute__((address_space(1))) unsigned int*)g,
        (__attribute__((address_space(3))) unsigned int*)l, 16, 0, 0);
}

// write-through stores: visible device-wide once vmcnt-complete, no dirty local-L2 line
__device__ __forceinline__ void store_short_wt(ushort_t* p, ushort_t v) {
    asm volatile("global_store_short %0, %1, off sc0 sc1"
                 : : "v"(p), "v"((unsigned int)v) : "memory");
}
__device__ __forceinline__ void store_uint_wt(unsigned int* p, unsigned int v) {
    asm volatile("global_store_dword %0, %1, off sc0 sc1"
                 : : "v"(p), "v"(v) : "memory");
}

// ---------------- Stage 0: f32 -> bf16 mirror of weights + h0; zero flags ----------------
__global__ void cvt_all(const float* __restrict__ vw, const float* __restrict__ sw,
                        const float* __restrict__ uw, const float* __restrict__ ww,
                        const float* __restrict__ cw, const float* __restrict__ h0,
                        ushort_t* __restrict__ mir, unsigned int* __restrict__ flg) {
    if (blockIdx.x == 0) {   // zero flags[32][64] (8 KiB); visible after kernel-end release
        int4 zz = {0, 0, 0, 0};
        ((int4*)flg)[threadIdx.x * 2 + 0] = zz;
        ((int4*)flg)[threadIdx.x * 2 + 1] = zz;
    }
    long idx = ((long)blockIdx.x * blockDim.x + threadIdx.x) * 8;
    const float* src; long off;
    if      (idx <  1048576L) { src = vw; off = idx; }
    else if (idx <  2097152L) { src = sw; off = idx - 1048576L; }
    else if (idx <  4194304L) { src = uw; off = idx - 2097152L; }
    else if (idx <  8388608L) { src = ww; off = idx - 4194304L; }
    else if (idx < 18628608L) { src = cw; off = idx - 8388608L; }
    else if (idx < 18694144L) { src = h0; off = idx - 18628608L; }
    else return;
    float4 a = *(const float4*)(src + off);
    float4 b = *(const float4*)(src + off + 4);
    ushort_t o[8];
    o[0] = f2bf(a.x); o[1] = f2bf(a.y); o[2] = f2bf(a.z); o[3] = f2bf(a.w);
    o[4] = f2bf(b.x); o[5] = f2bf(b.y); o[6] = f2bf(b.z); o[7] = f2bf(b.w);
    *(int4*)(mir + idx) = *(const int4*)o;
}

// ---------------- Stage A: x = [img ; B_emb[captions[:, :-1]]], f32 -> bf16 ----------------
__global__ void build_x(const int* __restrict__ cap,
                        const float* __restrict__ img,
                        const float* __restrict__ emb,
                        ushort_t* __restrict__ X) {
    int idx = blockIdx.x * blockDim.x + threadIdx.x;
    int row = idx >> 6;
    int c8  = (idx & 63) << 3;
    int b = row >> 5, t = row & 31;
    const float* src = (t == 0) ? (img + (size_t)b * Edim)
                                : (emb + (size_t)cap[b * Tdim + (t - 1)] * Edim);
    float4 a  = *(const float4*)(src + c8);
    float4 bb = *(const float4*)(src + c8 + 4);
    ushort_t o[8];
    o[0] = f2bf(a.x);  o[1] = f2bf(a.y);  o[2] = f2bf(a.z);  o[3] = f2bf(a.w);
    o[4] = f2bf(bb.x); o[5] = f2bf(bb.y); o[6] = f2bf(bb.z); o[7] = f2bf(bb.w);
    *(int4*)(X + (size_t)row * Edim + c8) = *(const int4*)o;
}

// ---------------- Generic GEMM: C[m][n] = sum_k A[m][k]*Bt[n][k] + bias[n] ----------------
// T2 LDS XOR-swizzle; T1 XCD remap; zpack: [t][cg][g][hc][b] layout for lstm_scan.
// aswap=1: logical A-row (b*32+t) is stored at physical row (t*64+b)  (Hbt layout).
__launch_bounds__(256)
__global__ void gemm_bt(const ushort_t* __restrict__ A, long lda, long gsA,
                        const ushort_t* __restrict__ Bm, long ldb, long gsB,
                        void* __restrict__ Cv, long ldc, long gsC,
                        const float* __restrict__ bias, long gsBias,
                        int N, int K, int f32out, int zpack, int aswap) {
    __shared__ ushort_t As[128 * 64];
    __shared__ ushort_t Bs[128 * 64];
    int z = blockIdx.z;
    A += (size_t)z * gsA; Bm += (size_t)z * gsB; bias += (size_t)z * gsBias;

    // T1: XCD-aware remap (per-z slab; slab sizes here are all %8==0)
    int nx = gridDim.x, ny = gridDim.y;
    int lin = blockIdx.x + nx * blockIdx.y;
    int per_xcd = (nx * ny) >> 3;
    int l2 = (lin & 7) * per_xcd + (lin >> 3);
    int bx = l2 / ny, by = l2 % ny;

    int tid = threadIdx.x;
    int w = tid >> 6, l = tid & 63;
    int wm = (w >> 1) * 64, wn = (w & 1) * 64;
    int m0 = by * 128, n0 = bx * 128;

    int srow = tid >> 3;
    int scol = (tid & 7) << 3;

    int lane_r = l & 15;
    int lane_k = (l >> 4) << 3;

    f32x4 zero = {0.f, 0.f, 0.f, 0.f};
    f32x4 acc[4][4];
#pragma unroll
    for (int i = 0; i < 4; i++)
#pragma unroll
        for (int j = 0; j < 4; j++) acc[i][j] = zero;

    for (int k0 = 0; k0 < K; k0 += 64) {
#pragma unroll
        for (int j = 0; j < 4; j++) {
            int r = srow + j * 32;
            int pr = m0 + r;
            if (aswap) pr = ((pr & 31) << 6) + (pr >> 5);
            int sc = scol ^ ((r & 7) << 3);
            gload_lds16(A + (size_t)pr * lda + k0 + sc, &As[r * 64 + scol]);
        }
#pragma unroll
        for (int j = 0; j < 4; j++) {
            int r = srow + j * 32;
            int br = n0 + r; if (br > N - 1) br = N - 1;
            int sc = scol ^ ((r & 7) << 3);
            gload_lds16(Bm + (size_t)br * ldb + k0 + sc, &Bs[r * 64 + scol]);
        }
        __syncthreads();
#pragma unroll
        for (int kk = 0; kk < 64; kk += 32) {
            bf16x8 af[4], bfr[4];
#pragma unroll
            for (int i = 0; i < 4; i++) {
                int ar = wm + i * 16 + lane_r;
                af[i] = *(const bf16x8*)&As[ar * 64 + ((kk + lane_k) ^ ((ar & 7) << 3))];
            }
#pragma unroll
            for (int j = 0; j < 4; j++) {
                int br2 = wn + j * 16 + lane_r;
                bfr[j] = *(const bf16x8*)&Bs[br2 * 64 + ((kk + lane_k) ^ ((br2 & 7) << 3))];
            }
#pragma unroll
            for (int i = 0; i < 4; i++)
#pragma unroll
                for (int j = 0; j < 4; j++)
                    acc[i][j] = __builtin_amdgcn_mfma_f32_16x16x32_bf16(af[i], bfr[j], acc[i][j], 0, 0, 0);
        }
        __syncthreads();
    }

    int row_base = m0 + wm + ((l >> 4) << 2);
    int col_base = n0 + wn + lane_r;
#pragma unroll
    for (int j = 0; j < 4; j++) {
        int col = col_base + j * 16;
        if (col < N) {
            float bv = bias[col];
#pragma unroll
            for (int i = 0; i < 4; i++) {
#pragma unroll
                for (int r = 0; r < 4; r++) {
                    int row = row_base + i * 16 + r;
                    float v = acc[i][j][r] + bv;
                    if (zpack) {
                        int b = row >> 5, tt = row & 31;
                        size_t idx = (((size_t)(tt * 64 + (col >> 4)) * 4 + z) * 16
                                      + (col & 15)) * 64 + b;
                        ((ushort_t*)Cv)[idx] = f2bf(v);
                    } else if (f32out) {
                        ((float*)Cv)[(size_t)z * gsC + (size_t)row * ldc + col] = v;
                    } else {
                        ((ushort_t*)Cv)[(size_t)z * gsC + (size_t)row * ldc + col] = f2bf(v);
                    }
                }
            }
        }
    }
}

// hand-issued 16B load with literal offset into ring slot i (compiler cannot serialize)
#define GLD(i, o) asm volatile("global_load_dwordx4 %0, %1, off offset:" o \
                               : "=v"(ab[i]) : "v"(apx))
// One k-chunk: ds_reads BEFORE the counted wait (overlap LDS latency with vmcnt wait);
// sched_barrier(0) is the ONLY verified fence vs MFMA hoisting past inline-asm waitcnt
// (rule #18 — round 8's mask 0x3F7 let MFMA hoist -> garbage). ISSUE refills the ring.
// NOTE (r11 lesson): do NOT add more live registers to this loop — r9's VGPR=132 is
// just under the allocator's spill threshold; spilled asm-output regs store garbage
// (spill stores get no vmcnt wait for asm outputs). Keep this structure EXACT.
#define CHUNK(d, n, ISSUE)                                                                   \
    do {                                                                                     \
        const int kc2 = ((d) * 32 + lane_kb) * 2;                                            \
        bf16x8 b0 = *(const bf16x8*)((const char*)Ws + ((     lane_r) * 2048 + (kc2 ^ swz)));\
        bf16x8 b1 = *(const bf16x8*)((const char*)Ws + ((16 + lane_r) * 2048 + (kc2 ^ swz)));\
        bf16x8 b2 = *(const bf16x8*)((const char*)Ws + ((32 + lane_r) * 2048 + (kc2 ^ swz)));\
        bf16x8 b3 = *(const bf16x8*)((const char*)Ws + ((48 + lane_r) * 2048 + (kc2 ^ swz)));\
        asm volatile("s_waitcnt vmcnt(" n ")");                                              \
        __builtin_amdgcn_sched_barrier(0);                                                   \
        bf16x8 av = __builtin_bit_cast(bf16x8, ab[(d) & 15]);                                \
        acc[0] = __builtin_amdgcn_mfma_f32_16x16x32_bf16(av, b0, acc[0], 0, 0, 0);           \
        acc[1] = __builtin_amdgcn_mfma_f32_16x16x32_bf16(av, b1, acc[1], 0, 0, 0);           \
        acc[2] = __builtin_amdgcn_mfma_f32_16x16x32_bf16(av, b2, acc[2], 0, 0, 0);           \
        acc[3] = __builtin_amdgcn_mfma_f32_16x16x32_bf16(av, b3, acc[3], 0, 0, 0);           \
        ISSUE;                                                                               \
    } while (0)

// ---------------- Stage E: persistent LSTM scan, flag dataflow + 16-deep asm ring ----------
// 64 blocks x 256 threads (cooperative). 1 block/CU -> 1 wave/SIMD -> zero TLP: h-chunk
// loads hand-issued (16 in flight, ring-refilled), consumed with counted vmcnt.
// Ring math: chunks 0..16 wait vmcnt(15) (issued grows with d), 17..31 wait 14..0.
__launch_bounds__(256, 1)
__global__ void lstm_scan(const ushort_t* __restrict__ Wm,   // bf16 [4*1024][1024]
                          const float* __restrict__ Wb,      // f32 [4][1024]
                          const ushort_t* __restrict__ zb,   // packed g3 [t][cg][g][hc][b]
                          const ushort_t* __restrict__ h0b,  // bf16 [64][1024]
                          const float* __restrict__ c0,      // f32 [64][1024]
                          ushort_t* __restrict__ Hbt,        // bf16 [t][64][1024]
                          unsigned int* __restrict__ flags) { // [32][64]
    __shared__ ushort_t Ws[64 * 1024];   // 128 KiB
    int cg = blockIdx.x;
    int tid = threadIdx.x;
    int w = tid >> 6, l = tid & 63;
    int lane_r = l & 15, lane_kb = (l >> 4) << 3;

    // ---- prologue: stage W slice into LDS with 16B XOR swizzle (reg-staged) ----
    for (int e = tid * 8; e < 65536; e += 2048) {
        int rowl = e >> 10, ke = e & 1023;
        int g = rowl >> 4, hc = rowl & 15;
        const ushort_t* src = Wm + ((size_t)(g * Hdim + cg * 16 + hc)) * Hdim + ke;
        int dstb = rowl * 2048 + ((ke * 2) ^ ((rowl & 7) << 4));
        *(int4*)((char*)Ws + dstb) = *(const int4*)src;
    }
    int hcol = cg * 16 + lane_r;
    float wbv[4];
#pragma unroll
    for (int g = 0; g < 4; g++) wbv[g] = Wb[g * Hdim + hcol];
    int rb0 = w * 16 + ((l >> 4) << 2);   // first of this thread's 4 batch rows
    float cst[4];
#pragma unroll
    for (int r = 0; r < 4; r++) cst[r] = c0[(size_t)(rb0 + r) * Hdim + hcol];
    __syncthreads();

    int arow = w * 16 + lane_r;
    int swz = (lane_r & 7) << 4;

    for (int t = 0; t < Tdim; t++) {
        // g3 loads for this step (independent of h) — issue before the poll
        ushort_t g3s[4][4];
        size_t zbase = ((size_t)t * 64 + cg) * 4096 + (size_t)lane_r * 64 + rb0;
#pragma unroll
        for (int g = 0; g < 4; g++)
            *(ushort4*)g3s[g] = *(const ushort4*)(zb + zbase + (size_t)g * 1024);

        // wait for ALL step-(t-1) producers: lane l watches flags[t-1][l]
        if (t > 0) {
            const unsigned int* fp = flags + (size_t)(t - 1) * 64 + l;
            unsigned int v;
            do {
                v = __hip_atomic_load(fp, __ATOMIC_RELAXED, __HIP_MEMORY_SCOPE_AGENT);
            } while (__ballot(v != 0) != 0xFFFFFFFFFFFFFFFFull);
        }
        __builtin_amdgcn_sched_barrier(0);   // nothing crosses the poll

        const ushort_t* hp = t ? (Hbt + (size_t)(t - 1) * (Bdim * Hdim)) : h0b;
        const ushort_t* apx = hp + (size_t)arow * Hdim + lane_kb;

        // prime the 16-deep ring (chunks 0..15; 64B apart)
        int4 ab[16];
        GLD(0, "0");    GLD(1, "64");   GLD(2, "128");  GLD(3, "192");
        GLD(4, "256");  GLD(5, "320");  GLD(6, "384");  GLD(7, "448");
        GLD(8, "512");  GLD(9, "576");  GLD(10, "640"); GLD(11, "704");
        GLD(12, "768"); GLD(13, "832"); GLD(14, "896"); GLD(15, "960");

        f32x4 zero = {0.f, 0.f, 0.f, 0.f};
        f32x4 acc[4];
#pragma unroll
        for (int g = 0; g < 4; g++) acc[g] = zero;

        CHUNK(0, "15", GLD(0, "1024"));  CHUNK(1, "15", GLD(1, "1088"));
        CHUNK(2, "15", GLD(2, "1152"));  CHUNK(3, "15", GLD(3, "1216"));
        CHUNK(4, "15", GLD(4, "1280"));  CHUNK(5, "15", GLD(5, "1344"));
        CHUNK(6, "15", GLD(6, "1408"));  CHUNK(7, "15", GLD(7, "1472"));
        CHUNK(8, "15", GLD(8, "1536"));  CHUNK(9, "15", GLD(9, "1600"));
        CHUNK(10, "15", GLD(10, "1664")); CHUNK(11, "15", GLD(11, "1728"));
        CHUNK(12, "15", GLD(12, "1792")); CHUNK(13, "15", GLD(13, "1856"));
        CHUNK(14, "15", GLD(14, "1920")); CHUNK(15, "15", GLD(15, "1984"));
        CHUNK(16, "15", (void)0); CHUNK(17, "14", (void)0);
        CHUNK(18, "13", (void)0); CHUNK(19, "12", (void)0);
        CHUNK(20, "11", (void)0); CHUNK(21, "10", (void)0);
        CHUNK(22, "9", (void)0);  CHUNK(23, "8", (void)0);
        CHUNK(24, "7", (void)0);  CHUNK(25, "6", (void)0);
        CHUNK(26, "5", (void)0);  CHUNK(27, "4", (void)0);
        CHUNK(28, "3", (void)0);  CHUNK(29, "2", (void)0);
        CHUNK(30, "1", (void)0);  CHUNK(31, "0", (void)0);

#pragma unroll
        for (int r = 0; r < 4; r++) {
            float zi = acc[0][r] + wbv[0] + bf2f(g3s[0][r]);
            float zf = acc[1][r] + wbv[1] + bf2f(g3s[1][r]);
            float zo = acc[2][r] + wbv[2] + bf2f(g3s[2][r]);
            float zc = acc[3][r] + wbv[3] + bf2f(g3s[3][r]);
            // fast gate math: v_exp + v_rcp approx (err ~1e-7 << bf16 rounding)
            float it = __builtin_amdgcn_rcpf(1.f + __expf(-zi));
            float ft = __builtin_amdgcn_rcpf(1.f + __expf(-zf));
            float ot = __builtin_amdgcn_rcpf(1.f + __expf(-zo));
            float e2 = __expf(-2.f * zc);
            float ct = (1.f - e2) * __builtin_amdgcn_rcpf(1.f + e2);
            float cn = ft * cst[r] + it * ct;
            cst[r] = cn;
            store_short_wt(Hbt + (size_t)t * (Bdim * Hdim) + (size_t)(rb0 + r) * Hdim + hcol,
                           f2bf(ot * cn));
        }

        // drain this wave's h stores, block-arrive, publish own flag (plain WT store)
        asm volatile("s_waitcnt vmcnt(0)" ::: "memory");
        __syncthreads();
        if (tid == 0) store_uint_wt(flags + (size_t)t * 64 + cg, 1u);
    }
}

extern "C" void kernel_launch(void* const* d_in, const int* in_sizes, int n_in,
                              void* d_out, int out_size, void* d_ws, size_t ws_size,
                              hipStream_t stream) {
    const int*   cap  = (const int*)d_in[0];
    const float* img  = (const float*)d_in[1];
    const float* Bemb = (const float*)d_in[2];
    const float* V_W  = (const float*)d_in[3];
    const float* V_b  = (const float*)d_in[4];
    const float* S_W  = (const float*)d_in[5];
    const float* S_b  = (const float*)d_in[6];
    const float* U_W  = (const float*)d_in[7];
    const float* U_b  = (const float*)d_in[8];
    const float* W_W  = (const float*)d_in[9];
    const float* W_b  = (const float*)d_in[10];
    const float* C_W  = (const float*)d_in[11];
    const float* C_b  = (const float*)d_in[12];
    const float* h0   = (const float*)d_in[13];
    const float* c0   = (const float*)d_in[14];

    char* ws = (char*)d_ws;
    ushort_t* mir = (ushort_t*)(ws);                       // 35.7 MiB bf16 mirror
    ushort_t* X   = (ushort_t*)(ws + (size_t)(36u << 20)); // 2 MiB
    ushort_t* g1  = (ushort_t*)(ws + (size_t)(38u << 20)); // 8 MiB
    ushort_t* g2  = (ushort_t*)(ws + (size_t)(46u << 20)); // 8 MiB
    ushort_t* Hbt = (ushort_t*)(ws + (size_t)(54u << 20)); // 4 MiB [t][b][h]
    unsigned int* flags = (unsigned int*)(ws + (size_t)(58u << 20)); // 8 KiB
    ushort_t* zb  = (ushort_t*)d_out;                      // 16 MiB scratch, dead before stage F

    const ushort_t* V_Wb = mir;
    const ushort_t* S_Wb = mir + 1048576L;
    const ushort_t* U_Wb = mir + 2097152L;
    const ushort_t* W_Wb = mir + 4194304L;
    const ushort_t* C_Wb = mir + 8388608L;
    const ushort_t* h0b  = mir + 18628608L;

    cvt_all<<<9128, 256, 0, stream>>>(V_W, S_W, U_W, W_W, C_W, h0, mir, flags);
    build_x<<<512, 256, 0, stream>>>(cap, img, Bemb, X);

    // Stage B: g1 = X (2048x512) * V_Wcat^T (2048x512) + V_b
    gemm_bt<<<dim3(16, 16, 1), 256, 0, stream>>>(X, 512, 0, V_Wb, 512, 0,
                                                 g1, 2048, 0, V_b, 0, 2048, 512, 0, 0, 0);
    // Stage C (per gate): g2[:, g] = g1[:, g] * S_W[g]^T + S_b[g]
    gemm_bt<<<dim3(4, 16, 4), 256, 0, stream>>>(g1, 2048, 512, S_Wb, 512, 512 * 512,
                                                g2, 2048, 512, S_b, 512, 512, 512, 0, 0, 0);
    // Stage D (per gate): zb(packed) = g2[:, g] * U_W[g]^T + U_b[g]
    gemm_bt<<<dim3(8, 16, 4), 256, 0, stream>>>(g2, 2048, 512, U_Wb, 512, 1024 * 512,
                                                zb, 0, 0, U_b, 1024, 1024, 512, 0, 1, 0);
    // Stage E: persistent scan — cooperative launch guarantees co-residency
    {
        const ushort_t* a0 = W_Wb; const float* a1 = W_b; const ushort_t* a2 = zb;
        const ushort_t* a3 = h0b;  const float* a4 = c0;  ushort_t* a5 = Hbt;
        unsigned int* a6 = flags;
        void* sargs[7] = {(void*)&a0, (void*)&a1, (void*)&a2, (void*)&a3,
                          (void*)&a4, (void*)&a5, (void*)&a6};
        hipLaunchCooperativeKernel((const void*)lstm_scan, dim3(SCAN_BLOCKS), dim3(256),
                                   sargs, 0, stream);
    }
    // Stage F: out = Hbt([t][b][h], aswap) (2048x1024) * C_W^T (10000x1024) + C_b (f32 out)
    gemm_bt<<<dim3(79, 16, 1), 256, 0, stream>>>(Hbt, 1024, 0, C_Wb, 1024, 0,
                                                 d_out, 10000, 0, C_b, 0,
                                                 10000, 1024, 1, 0, 1);
}

// Round 13
// 381.511 us; speedup vs baseline: 1.4297x; 1.0064x over previous
//
#include <hip/hip_runtime.h>
#include <hip/hip_bf16.h>

typedef __attribute__((ext_vector_type(8))) __bf16 bf16x8;
typedef __attribute__((ext_vector_type(4))) float f32x4;
typedef unsigned short ushort_t;

#define Bdim 64
#define Tdim 32
#define Edim 512
#define Fdim 512
#define Hdim 1024
#define Vdim 10000
#define SCAN_BLOCKS 64
#define CONS_BLOCKS 157   // ceil(10000/64) consumer blocks for fused logits

__device__ __forceinline__ float bf2f(ushort_t u) {
    unsigned int x = ((unsigned int)u) << 16;
    union { unsigned int i; float f; } c; c.i = x; return c.f;
}
__device__ __forceinline__ ushort_t f2bf(float f) {
    __hip_bfloat16 h = __float2bfloat16(f);
    union { __hip_bfloat16 h; ushort_t u; } c; c.h = h; return c.u;
}

__device__ __forceinline__ void gload_lds16(const void* g, void* l) {
    __builtin_amdgcn_global_load_lds(
        (const __attribute__((address_space(1))) unsigned int*)g,
        (__attribute__((address_space(3))) unsigned int*)l, 16, 0, 0);
}

// write-through stores: visible device-wide once vmcnt-complete, no dirty local-L2 line
__device__ __forceinline__ void store_short_wt(ushort_t* p, ushort_t v) {
    asm volatile("global_store_short %0, %1, off sc0 sc1"
                 : : "v"(p), "v"((unsigned int)v) : "memory");
}
__device__ __forceinline__ void store_uint_wt(unsigned int* p, unsigned int v) {
    asm volatile("global_store_dword %0, %1, off sc0 sc1"
                 : : "v"(p), "v"(v) : "memory");
}

// ---------------- Stage 0: f32 -> bf16 mirror of weights + h0; zero flags ----------------
__global__ void cvt_all(const float* __restrict__ vw, const float* __restrict__ sw,
                        const float* __restrict__ uw, const float* __restrict__ ww,
                        const float* __restrict__ cw, const float* __restrict__ h0,
                        ushort_t* __restrict__ mir, unsigned int* __restrict__ flg) {
    if (blockIdx.x == 0) {   // zero flags[32][64] (8 KiB); visible after kernel-end release
        int4 zz = {0, 0, 0, 0};
        ((int4*)flg)[threadIdx.x * 2 + 0] = zz;
        ((int4*)flg)[threadIdx.x * 2 + 1] = zz;
    }
    long idx = ((long)blockIdx.x * blockDim.x + threadIdx.x) * 8;
    const float* src; long off;
    if      (idx <  1048576L) { src = vw; off = idx; }
    else if (idx <  2097152L) { src = sw; off = idx - 1048576L; }
    else if (idx <  4194304L) { src = uw; off = idx - 2097152L; }
    else if (idx <  8388608L) { src = ww; off = idx - 4194304L; }
    else if (idx < 18628608L) { src = cw; off = idx - 8388608L; }
    else if (idx < 18694144L) { src = h0; off = idx - 18628608L; }
    else return;
    float4 a = *(const float4*)(src + off);
    float4 b = *(const float4*)(src + off + 4);
    ushort_t o[8];
    o[0] = f2bf(a.x); o[1] = f2bf(a.y); o[2] = f2bf(a.z); o[3] = f2bf(a.w);
    o[4] = f2bf(b.x); o[5] = f2bf(b.y); o[6] = f2bf(b.z); o[7] = f2bf(b.w);
    *(int4*)(mir + idx) = *(const int4*)o;
}

// ---------------- Stage A: x = [img ; B_emb[captions[:, :-1]]], f32 -> bf16 ----------------
__global__ void build_x(const int* __restrict__ cap,
                        const float* __restrict__ img,
                        const float* __restrict__ emb,
                        ushort_t* __restrict__ X) {
    int idx = blockIdx.x * blockDim.x + threadIdx.x;
    int row = idx >> 6;
    int c8  = (idx & 63) << 3;
    int b = row >> 5, t = row & 31;
    const float* src = (t == 0) ? (img + (size_t)b * Edim)
                                : (emb + (size_t)cap[b * Tdim + (t - 1)] * Edim);
    float4 a  = *(const float4*)(src + c8);
    float4 bb = *(const float4*)(src + c8 + 4);
    ushort_t o[8];
    o[0] = f2bf(a.x);  o[1] = f2bf(a.y);  o[2] = f2bf(a.z);  o[3] = f2bf(a.w);
    o[4] = f2bf(bb.x); o[5] = f2bf(bb.y); o[6] = f2bf(bb.z); o[7] = f2bf(bb.w);
    *(int4*)(X + (size_t)row * Edim + c8) = *(const int4*)o;
}

// ---------------- Generic GEMM: C[m][n] = sum_k A[m][k]*Bt[n][k] + bias[n] ----------------
// T2 LDS XOR-swizzle; T1 XCD remap; zpack: [t][cg][g][hc][b] layout for lstm_scan.
// aswap=1: logical A-row (b*32+t) is stored at physical row (t*64+b)  (Hbt layout).
__launch_bounds__(256)
__global__ void gemm_bt(const ushort_t* __restrict__ A, long lda, long gsA,
                        const ushort_t* __restrict__ Bm, long ldb, long gsB,
                        void* __restrict__ Cv, long ldc, long gsC,
                        const float* __restrict__ bias, long gsBias,
                        int N, int K, int f32out, int zpack, int aswap) {
    __shared__ ushort_t As[128 * 64];
    __shared__ ushort_t Bs[128 * 64];
    int z = blockIdx.z;
    A += (size_t)z * gsA; Bm += (size_t)z * gsB; bias += (size_t)z * gsBias;

    int nx = gridDim.x, ny = gridDim.y;
    int lin = blockIdx.x + nx * blockIdx.y;
    int per_xcd = (nx * ny) >> 3;
    int l2 = (lin & 7) * per_xcd + (lin >> 3);
    int bx = l2 / ny, by = l2 % ny;

    int tid = threadIdx.x;
    int w = tid >> 6, l = tid & 63;
    int wm = (w >> 1) * 64, wn = (w & 1) * 64;
    int m0 = by * 128, n0 = bx * 128;

    int srow = tid >> 3;
    int scol = (tid & 7) << 3;

    int lane_r = l & 15;
    int lane_k = (l >> 4) << 3;

    f32x4 zero = {0.f, 0.f, 0.f, 0.f};
    f32x4 acc[4][4];
#pragma unroll
    for (int i = 0; i < 4; i++)
#pragma unroll
        for (int j = 0; j < 4; j++) acc[i][j] = zero;

    for (int k0 = 0; k0 < K; k0 += 64) {
#pragma unroll
        for (int j = 0; j < 4; j++) {
            int r = srow + j * 32;
            int pr = m0 + r;
            if (aswap) pr = ((pr & 31) << 6) + (pr >> 5);
            int sc = scol ^ ((r & 7) << 3);
            gload_lds16(A + (size_t)pr * lda + k0 + sc, &As[r * 64 + scol]);
        }
#pragma unroll
        for (int j = 0; j < 4; j++) {
            int r = srow + j * 32;
            int br = n0 + r; if (br > N - 1) br = N - 1;
            int sc = scol ^ ((r & 7) << 3);
            gload_lds16(Bm + (size_t)br * ldb + k0 + sc, &Bs[r * 64 + scol]);
        }
        __syncthreads();
#pragma unroll
        for (int kk = 0; kk < 64; kk += 32) {
            bf16x8 af[4], bfr[4];
#pragma unroll
            for (int i = 0; i < 4; i++) {
                int ar = wm + i * 16 + lane_r;
                af[i] = *(const bf16x8*)&As[ar * 64 + ((kk + lane_k) ^ ((ar & 7) << 3))];
            }
#pragma unroll
            for (int j = 0; j < 4; j++) {
                int br2 = wn + j * 16 + lane_r;
                bfr[j] = *(const bf16x8*)&Bs[br2 * 64 + ((kk + lane_k) ^ ((br2 & 7) << 3))];
            }
#pragma unroll
            for (int i = 0; i < 4; i++)
#pragma unroll
                for (int j = 0; j < 4; j++)
                    acc[i][j] = __builtin_amdgcn_mfma_f32_16x16x32_bf16(af[i], bfr[j], acc[i][j], 0, 0, 0);
        }
        __syncthreads();
    }

    int row_base = m0 + wm + ((l >> 4) << 2);
    int col_base = n0 + wn + lane_r;
#pragma unroll
    for (int j = 0; j < 4; j++) {
        int col = col_base + j * 16;
        if (col < N) {
            float bv = bias[col];
#pragma unroll
            for (int i = 0; i < 4; i++) {
#pragma unroll
                for (int r = 0; r < 4; r++) {
                    int row = row_base + i * 16 + r;
                    float v = acc[i][j][r] + bv;
                    if (zpack) {
                        int b = row >> 5, tt = row & 31;
                        size_t idx = (((size_t)(tt * 64 + (col >> 4)) * 4 + z) * 16
                                      + (col & 15)) * 64 + b;
                        ((ushort_t*)Cv)[idx] = f2bf(v);
                    } else if (f32out) {
                        ((float*)Cv)[(size_t)z * gsC + (size_t)row * ldc + col] = v;
                    } else {
                        ((ushort_t*)Cv)[(size_t)z * gsC + (size_t)row * ldc + col] = f2bf(v);
                    }
                }
            }
        }
    }
}

// hand-issued 16B load with literal offset into ring slot i (compiler cannot serialize)
#define GLD(i, o) asm volatile("global_load_dwordx4 %0, %1, off offset:" o \
                               : "=v"(ab[i]) : "v"(apx))
// One k-chunk: ds_reads BEFORE the counted wait; sched_barrier(0) is the ONLY verified
// fence vs MFMA hoisting past inline-asm waitcnt (rule #18). Keep register count EXACT
// (r11: extra live VGPRs -> spilled asm-output regs store garbage).
#define CHUNK(d, n, ISSUE)                                                                   \
    do {                                                                                     \
        const int kc2 = ((d) * 32 + lane_kb) * 2;                                            \
        bf16x8 b0 = *(const bf16x8*)((const char*)Ws + ((     lane_r) * 2048 + (kc2 ^ swz)));\
        bf16x8 b1 = *(const bf16x8*)((const char*)Ws + ((16 + lane_r) * 2048 + (kc2 ^ swz)));\
        bf16x8 b2 = *(const bf16x8*)((const char*)Ws + ((32 + lane_r) * 2048 + (kc2 ^ swz)));\
        bf16x8 b3 = *(const bf16x8*)((const char*)Ws + ((48 + lane_r) * 2048 + (kc2 ^ swz)));\
        asm volatile("s_waitcnt vmcnt(" n ")");                                              \
        __builtin_amdgcn_sched_barrier(0);                                                   \
        bf16x8 av = __builtin_bit_cast(bf16x8, ab[(d) & 15]);                                \
        acc[0] = __builtin_amdgcn_mfma_f32_16x16x32_bf16(av, b0, acc[0], 0, 0, 0);           \
        acc[1] = __builtin_amdgcn_mfma_f32_16x16x32_bf16(av, b1, acc[1], 0, 0, 0);           \
        acc[2] = __builtin_amdgcn_mfma_f32_16x16x32_bf16(av, b2, acc[2], 0, 0, 0);           \
        acc[3] = __builtin_amdgcn_mfma_f32_16x16x32_bf16(av, b3, acc[3], 0, 0, 0);           \
        ISSUE;                                                                               \
    } while (0)
// full 32-chunk K=1024 loop: prime 16-deep ring, consume with counted vmcnt, ring-refill
#define KLOOP32()                                                                            \
    int4 ab[16];                                                                             \
    GLD(0, "0");    GLD(1, "64");   GLD(2, "128");  GLD(3, "192");                           \
    GLD(4, "256");  GLD(5, "320");  GLD(6, "384");  GLD(7, "448");                           \
    GLD(8, "512");  GLD(9, "576");  GLD(10, "640"); GLD(11, "704");                          \
    GLD(12, "768"); GLD(13, "832"); GLD(14, "896"); GLD(15, "960");                          \
    CHUNK(0, "15", GLD(0, "1024"));  CHUNK(1, "15", GLD(1, "1088"));                         \
    CHUNK(2, "15", GLD(2, "1152"));  CHUNK(3, "15", GLD(3, "1216"));                         \
    CHUNK(4, "15", GLD(4, "1280"));  CHUNK(5, "15", GLD(5, "1344"));                         \
    CHUNK(6, "15", GLD(6, "1408"));  CHUNK(7, "15", GLD(7, "1472"));                         \
    CHUNK(8, "15", GLD(8, "1536"));  CHUNK(9, "15", GLD(9, "1600"));                         \
    CHUNK(10, "15", GLD(10, "1664")); CHUNK(11, "15", GLD(11, "1728"));                      \
    CHUNK(12, "15", GLD(12, "1792")); CHUNK(13, "15", GLD(13, "1856"));                      \
    CHUNK(14, "15", GLD(14, "1920")); CHUNK(15, "15", GLD(15, "1984"));                      \
    CHUNK(16, "15", (void)0); CHUNK(17, "14", (void)0);                                      \
    CHUNK(18, "13", (void)0); CHUNK(19, "12", (void)0);                                      \
    CHUNK(20, "11", (void)0); CHUNK(21, "10", (void)0);                                      \
    CHUNK(22, "9", (void)0);  CHUNK(23, "8", (void)0);                                       \
    CHUNK(24, "7", (void)0);  CHUNK(25, "6", (void)0);                                       \
    CHUNK(26, "5", (void)0);  CHUNK(27, "4", (void)0);                                       \
    CHUNK(28, "3", (void)0);  CHUNK(29, "2", (void)0);                                       \
    CHUNK(30, "1", (void)0);  CHUNK(31, "0", (void)0)

// ---------------- Stage E+F fused: persistent scan + streaming logits ----------------
// Cooperative launch. Blocks 0..63: the validated r9/r12 LSTM scan (unchanged).
// Blocks 64..220: consumer block j owns 64 logits cols; stages its C_W panel in LDS
// once, then per t waits flags[t] and computes the 64x64x1024 logits tile with the
// SAME k-loop macros. Consumers only wait on flags -> no added deadlock risk.
__launch_bounds__(256, 1)
__global__ void lstm_fused(const ushort_t* __restrict__ Wm,   // bf16 [4*1024][1024]
                           const float* __restrict__ Wb,      // f32 [4][1024]
                           const ushort_t* __restrict__ zb,   // packed g3 [t][cg][g][hc][b]
                           const ushort_t* __restrict__ h0b,  // bf16 [64][1024]
                           const float* __restrict__ c0,      // f32 [64][1024]
                           ushort_t* __restrict__ Hbt,        // bf16 [t][64][1024]
                           unsigned int* __restrict__ flags,  // [32][64]
                           const ushort_t* __restrict__ CWb,  // bf16 [10000][1024]
                           const float* __restrict__ Cb,      // f32 [10000]
                           float* __restrict__ out) {         // f32 [64][32][10000]
    __shared__ ushort_t Ws[64 * 1024];   // 128 KiB
    int bid = blockIdx.x;
    int tid = threadIdx.x;
    int w = tid >> 6, l = tid & 63;
    int lane_r = l & 15, lane_kb = (l >> 4) << 3;

    if (bid < SCAN_BLOCKS) {
        // ================= SCAN ROLE (r12 body, unchanged) =================
        int cg = bid;
        for (int e = tid * 8; e < 65536; e += 2048) {
            int rowl = e >> 10, ke = e & 1023;
            int g = rowl >> 4, hc = rowl & 15;
            const ushort_t* src = Wm + ((size_t)(g * Hdim + cg * 16 + hc)) * Hdim + ke;
            int dstb = rowl * 2048 + ((ke * 2) ^ ((rowl & 7) << 4));
            *(int4*)((char*)Ws + dstb) = *(const int4*)src;
        }
        int hcol = cg * 16 + lane_r;
        float wbv[4];
#pragma unroll
        for (int g = 0; g < 4; g++) wbv[g] = Wb[g * Hdim + hcol];
        int rb0 = w * 16 + ((l >> 4) << 2);
        float cst[4];
#pragma unroll
        for (int r = 0; r < 4; r++) cst[r] = c0[(size_t)(rb0 + r) * Hdim + hcol];
        __syncthreads();

        int arow = w * 16 + lane_r;
        int swz = (lane_r & 7) << 4;

        for (int t = 0; t < Tdim; t++) {
            ushort_t g3s[4][4];
            size_t zbase = ((size_t)t * 64 + cg) * 4096 + (size_t)lane_r * 64 + rb0;
#pragma unroll
            for (int g = 0; g < 4; g++)
                *(ushort4*)g3s[g] = *(const ushort4*)(zb + zbase + (size_t)g * 1024);

            if (t > 0) {
                const unsigned int* fp = flags + (size_t)(t - 1) * 64 + l;
                unsigned int v;
                do {
                    v = __hip_atomic_load(fp, __ATOMIC_RELAXED, __HIP_MEMORY_SCOPE_AGENT);
                } while (__ballot(v != 0) != 0xFFFFFFFFFFFFFFFFull);
            }
            __builtin_amdgcn_sched_barrier(0);

            const ushort_t* hp = t ? (Hbt + (size_t)(t - 1) * (Bdim * Hdim)) : h0b;
            const ushort_t* apx = hp + (size_t)arow * Hdim + lane_kb;

            f32x4 zero = {0.f, 0.f, 0.f, 0.f};
            f32x4 acc[4];
#pragma unroll
            for (int g = 0; g < 4; g++) acc[g] = zero;

            KLOOP32();

#pragma unroll
            for (int r = 0; r < 4; r++) {
                float zi = acc[0][r] + wbv[0] + bf2f(g3s[0][r]);
                float zf = acc[1][r] + wbv[1] + bf2f(g3s[1][r]);
                float zo = acc[2][r] + wbv[2] + bf2f(g3s[2][r]);
                float zc = acc[3][r] + wbv[3] + bf2f(g3s[3][r]);
                float it = __builtin_amdgcn_rcpf(1.f + __expf(-zi));
                float ft = __builtin_amdgcn_rcpf(1.f + __expf(-zf));
                float ot = __builtin_amdgcn_rcpf(1.f + __expf(-zo));
                float e2 = __expf(-2.f * zc);
                float ct = (1.f - e2) * __builtin_amdgcn_rcpf(1.f + e2);
                float cn = ft * cst[r] + it * ct;
                cst[r] = cn;
                store_short_wt(Hbt + (size_t)t * (Bdim * Hdim) + (size_t)(rb0 + r) * Hdim + hcol,
                               f2bf(ot * cn));
            }

            asm volatile("s_waitcnt vmcnt(0)" ::: "memory");
            __syncthreads();
            if (tid == 0) store_uint_wt(flags + (size_t)t * 64 + cg, 1u);
        }
    } else {
        // ================= CONSUMER ROLE: logits cols [j*64, j*64+64) =================
        int j = bid - SCAN_BLOCKS;
        for (int e = tid * 8; e < 65536; e += 2048) {
            int rowl = e >> 10, ke = e & 1023;
            int n = j * 64 + rowl; if (n > Vdim - 1) n = Vdim - 1;
            const ushort_t* src = CWb + (size_t)n * Hdim + ke;
            int dstb = rowl * 2048 + ((ke * 2) ^ ((rowl & 7) << 4));
            *(int4*)((char*)Ws + dstb) = *(const int4*)src;
        }
        int rb0 = w * 16 + ((l >> 4) << 2);
        int arow = w * 16 + lane_r;
        int swz = (lane_r & 7) << 4;
        float cbv[4];
#pragma unroll
        for (int g = 0; g < 4; g++) {
            int col = j * 64 + g * 16 + lane_r;
            cbv[g] = Cb[col > Vdim - 1 ? Vdim - 1 : col];
        }
        __syncthreads();

        for (int t = 0; t < Tdim; t++) {
            // wave 0 waits for all 64 step-t producers; s_sleep throttles poll traffic
            if (w == 0) {
                const unsigned int* fp = flags + (size_t)t * 64 + l;
                unsigned int v;
                do {
                    __builtin_amdgcn_s_sleep(8);
                    v = __hip_atomic_load(fp, __ATOMIC_RELAXED, __HIP_MEMORY_SCOPE_AGENT);
                } while (__ballot(v != 0) != 0xFFFFFFFFFFFFFFFFull);
            }
            __syncthreads();
            __builtin_amdgcn_sched_barrier(0);

            const ushort_t* apx = Hbt + (size_t)t * (Bdim * Hdim) + (size_t)arow * Hdim + lane_kb;

            f32x4 zero = {0.f, 0.f, 0.f, 0.f};
            f32x4 acc[4];
#pragma unroll
            for (int g = 0; g < 4; g++) acc[g] = zero;

            KLOOP32();

#pragma unroll
            for (int g = 0; g < 4; g++) {
                int col = j * 64 + g * 16 + lane_r;
                if (col < Vdim) {
#pragma unroll
                    for (int r = 0; r < 4; r++)
                        out[((size_t)(rb0 + r) * Tdim + t) * Vdim + col] = acc[g][r] + cbv[g];
                }
            }
        }
    }
}

extern "C" void kernel_launch(void* const* d_in, const int* in_sizes, int n_in,
                              void* d_out, int out_size, void* d_ws, size_t ws_size,
                              hipStream_t stream) {
    const int*   cap  = (const int*)d_in[0];
    const float* img  = (const float*)d_in[1];
    const float* Bemb = (const float*)d_in[2];
    const float* V_W  = (const float*)d_in[3];
    const float* V_b  = (const float*)d_in[4];
    const float* S_W  = (const float*)d_in[5];
    const float* S_b  = (const float*)d_in[6];
    const float* U_W  = (const float*)d_in[7];
    const float* U_b  = (const float*)d_in[8];
    const float* W_W  = (const float*)d_in[9];
    const float* W_b  = (const float*)d_in[10];
    const float* C_W  = (const float*)d_in[11];
    const float* C_b  = (const float*)d_in[12];
    const float* h0   = (const float*)d_in[13];
    const float* c0   = (const float*)d_in[14];

    char* ws = (char*)d_ws;
    int fused = ws_size >= (size_t)(64u) * 1024 * 1024;

    ushort_t* mir = (ushort_t*)(ws);                              // 35.66 MiB bf16 mirror
    ushort_t* X   = (ushort_t*)(ws + (size_t)(36u << 20));        // 2 MiB (dead after B)
    ushort_t* g1  = (ushort_t*)(ws + (size_t)(38u << 20));        // 8 MiB (dead after C)
    ushort_t *g2, *Hbt, *zbp; unsigned int* flags;
    if (fused) {
        // lifetime-overlapped layout (64 MiB): zb [36,52) over dead X+g1; g2 [52,60); Hbt [60,64)
        zbp   = (ushort_t*)(ws + (size_t)(36u << 20));
        g2    = (ushort_t*)(ws + (size_t)(52u << 20));
        Hbt   = (ushort_t*)(ws + (size_t)(60u << 20));
        flags = (unsigned int*)(ws + (size_t)(36u << 20) - 16384); // 8 KiB in mir tail gap
    } else {
        // r12 fallback layout: zb in d_out (dead before stage F)
        zbp   = (ushort_t*)d_out;
        g2    = (ushort_t*)(ws + (size_t)(46u << 20));
        Hbt   = (ushort_t*)(ws + (size_t)(54u << 20));
        flags = (unsigned int*)(ws + (size_t)(58u << 20));
    }

    const ushort_t* V_Wb = mir;
    const ushort_t* S_Wb = mir + 1048576L;
    const ushort_t* U_Wb = mir + 2097152L;
    const ushort_t* W_Wb = mir + 4194304L;
    const ushort_t* C_Wb = mir + 8388608L;
    const ushort_t* h0b  = mir + 18628608L;

    cvt_all<<<9128, 256, 0, stream>>>(V_W, S_W, U_W, W_W, C_W, h0, mir, flags);
    build_x<<<512, 256, 0, stream>>>(cap, img, Bemb, X);

    // Stage B: g1 = X (2048x512) * V_Wcat^T (2048x512) + V_b
    gemm_bt<<<dim3(16, 16, 1), 256, 0, stream>>>(X, 512, 0, V_Wb, 512, 0,
                                                 g1, 2048, 0, V_b, 0, 2048, 512, 0, 0, 0);
    // Stage C (per gate): g2[:, g] = g1[:, g] * S_W[g]^T + S_b[g]
    gemm_bt<<<dim3(4, 16, 4), 256, 0, stream>>>(g1, 2048, 512, S_Wb, 512, 512 * 512,
                                                g2, 2048, 512, S_b, 512, 512, 512, 0, 0, 0);
    // Stage D (per gate): zb(packed) = g2[:, g] * U_W[g]^T + U_b[g]
    gemm_bt<<<dim3(8, 16, 4), 256, 0, stream>>>(g2, 2048, 512, U_Wb, 512, 1024 * 512,
                                                zbp, 0, 0, U_b, 1024, 1024, 512, 0, 1, 0);
    // Stage E(+F if fused): cooperative launch
    {
        const ushort_t* a0 = W_Wb; const float* a1 = W_b; const ushort_t* a2 = zbp;
        const ushort_t* a3 = h0b;  const float* a4 = c0;  ushort_t* a5 = Hbt;
        unsigned int* a6 = flags;  const ushort_t* a7 = C_Wb; const float* a8 = C_b;
        float* a9 = (float*)d_out;
        void* sargs[10] = {(void*)&a0, (void*)&a1, (void*)&a2, (void*)&a3, (void*)&a4,
                           (void*)&a5, (void*)&a6, (void*)&a7, (void*)&a8, (void*)&a9};
        int grid = fused ? (SCAN_BLOCKS + CONS_BLOCKS) : SCAN_BLOCKS;
        hipLaunchCooperativeKernel((const void*)lstm_fused, dim3(grid), dim3(256),
                                   sargs, 0, stream);
    }
    if (!fused) {
        // Stage F fallback: out = Hbt([t][b][h], aswap) * C_W^T + C_b (f32 out)
        gemm_bt<<<dim3(79, 16, 1), 256, 0, stream>>>(Hbt, 1024, 0, C_Wb, 1024, 0,
                                                     d_out, 10000, 0, C_b, 0,
                                                     10000, 1024, 1, 0, 1);
    }
}

// Round 14
// 332.155 us; speedup vs baseline: 1.6421x; 1.1486x over previous
//
#include <hip/hip_runtime.h>
#include <hip/hip_bf16.h>

typedef __attribute__((ext_vector_type(8))) __bf16 bf16x8;
typedef __attribute__((ext_vector_type(4))) float f32x4;
typedef unsigned short ushort_t;

#define Bdim 64
#define Tdim 32
#define Edim 512
#define Fdim 512
#define Hdim 1024
#define Vdim 10000
#define SCAN_BLOCKS 64
#define CONS_BLOCKS 157   // ceil(10000/64) consumer blocks for fused logits

__device__ __forceinline__ float bf2f(ushort_t u) {
    unsigned int x = ((unsigned int)u) << 16;
    union { unsigned int i; float f; } c; c.i = x; return c.f;
}
__device__ __forceinline__ ushort_t f2bf(float f) {
    __hip_bfloat16 h = __float2bfloat16(f);
    union { __hip_bfloat16 h; ushort_t u; } c; c.h = h; return c.u;
}

__device__ __forceinline__ void gload_lds16(const void* g, void* l) {
    __builtin_amdgcn_global_load_lds(
        (const __attribute__((address_space(1))) unsigned int*)g,
        (__attribute__((address_space(3))) unsigned int*)l, 16, 0, 0);
}

// write-through stores: visible device-wide once vmcnt-complete, no dirty local-L2 line
__device__ __forceinline__ void store_short_wt(ushort_t* p, ushort_t v) {
    asm volatile("global_store_short %0, %1, off sc0 sc1"
                 : : "v"(p), "v"((unsigned int)v) : "memory");
}
__device__ __forceinline__ void store_uint_wt(unsigned int* p, unsigned int v) {
    asm volatile("global_store_dword %0, %1, off sc0 sc1"
                 : : "v"(p), "v"(v) : "memory");
}

// ---------------- Stage 0: f32 -> bf16 mirror; zero flags+done ----------------
// mirror layout (elements): V_W 0 | S_W 1048576 | U_W 2097152 | W_W 4194304 |
//   h0 8388608 | C_W 8454144 .. 18694144.  Fused mode converts only idx<8454144
//   (C_W handled by consumer blocks inline); fallback converts everything.
__global__ void cvt_all(const float* __restrict__ vw, const float* __restrict__ sw,
                        const float* __restrict__ uw, const float* __restrict__ ww,
                        const float* __restrict__ h0, const float* __restrict__ cw,
                        ushort_t* __restrict__ mir, unsigned int* __restrict__ flg) {
    if (blockIdx.x == 0) {   // zero 16 KiB flags[32][64] + done[32] region
        int4 zz = {0, 0, 0, 0};
#pragma unroll
        for (int q = 0; q < 4; q++) ((int4*)flg)[threadIdx.x * 4 + q] = zz;
    }
    long idx = ((long)blockIdx.x * blockDim.x + threadIdx.x) * 8;
    const float* src; long off;
    if      (idx <  1048576L) { src = vw; off = idx; }
    else if (idx <  2097152L) { src = sw; off = idx - 1048576L; }
    else if (idx <  4194304L) { src = uw; off = idx - 2097152L; }
    else if (idx <  8388608L) { src = ww; off = idx - 4194304L; }
    else if (idx <  8454144L) { src = h0; off = idx - 8388608L; }
    else if (idx < 18694144L) { src = cw; off = idx - 8454144L; }
    else return;
    float4 a = *(const float4*)(src + off);
    float4 b = *(const float4*)(src + off + 4);
    ushort_t o[8];
    o[0] = f2bf(a.x); o[1] = f2bf(a.y); o[2] = f2bf(a.z); o[3] = f2bf(a.w);
    o[4] = f2bf(b.x); o[5] = f2bf(b.y); o[6] = f2bf(b.z); o[7] = f2bf(b.w);
    *(int4*)(mir + idx) = *(const int4*)o;
}

// ---------------- Stage A: x = [img ; B_emb[captions[:, :-1]]], f32 -> bf16 ----------------
__global__ void build_x(const int* __restrict__ cap,
                        const float* __restrict__ img,
                        const float* __restrict__ emb,
                        ushort_t* __restrict__ X) {
    int idx = blockIdx.x * blockDim.x + threadIdx.x;
    int row = idx >> 6;
    int c8  = (idx & 63) << 3;
    int b = row >> 5, t = row & 31;
    const float* src = (t == 0) ? (img + (size_t)b * Edim)
                                : (emb + (size_t)cap[b * Tdim + (t - 1)] * Edim);
    float4 a  = *(const float4*)(src + c8);
    float4 bb = *(const float4*)(src + c8 + 4);
    ushort_t o[8];
    o[0] = f2bf(a.x);  o[1] = f2bf(a.y);  o[2] = f2bf(a.z);  o[3] = f2bf(a.w);
    o[4] = f2bf(bb.x); o[5] = f2bf(bb.y); o[6] = f2bf(bb.z); o[7] = f2bf(bb.w);
    *(int4*)(X + (size_t)row * Edim + c8) = *(const int4*)o;
}

// ---------------- Generic GEMM: C[m][n] = sum_k A[m][k]*Bt[n][k] + bias[n] ----------------
__launch_bounds__(256)
__global__ void gemm_bt(const ushort_t* __restrict__ A, long lda, long gsA,
                        const ushort_t* __restrict__ Bm, long ldb, long gsB,
                        void* __restrict__ Cv, long ldc, long gsC,
                        const float* __restrict__ bias, long gsBias,
                        int N, int K, int f32out, int zpack, int aswap) {
    __shared__ ushort_t As[128 * 64];
    __shared__ ushort_t Bs[128 * 64];
    int z = blockIdx.z;
    A += (size_t)z * gsA; Bm += (size_t)z * gsB; bias += (size_t)z * gsBias;

    int nx = gridDim.x, ny = gridDim.y;
    int lin = blockIdx.x + nx * blockIdx.y;
    int per_xcd = (nx * ny) >> 3;
    int l2 = (lin & 7) * per_xcd + (lin >> 3);
    int bx = l2 / ny, by = l2 % ny;

    int tid = threadIdx.x;
    int w = tid >> 6, l = tid & 63;
    int wm = (w >> 1) * 64, wn = (w & 1) * 64;
    int m0 = by * 128, n0 = bx * 128;

    int srow = tid >> 3;
    int scol = (tid & 7) << 3;

    int lane_r = l & 15;
    int lane_k = (l >> 4) << 3;

    f32x4 zero = {0.f, 0.f, 0.f, 0.f};
    f32x4 acc[4][4];
#pragma unroll
    for (int i = 0; i < 4; i++)
#pragma unroll
        for (int j = 0; j < 4; j++) acc[i][j] = zero;

    for (int k0 = 0; k0 < K; k0 += 64) {
#pragma unroll
        for (int j = 0; j < 4; j++) {
            int r = srow + j * 32;
            int pr = m0 + r;
            if (aswap) pr = ((pr & 31) << 6) + (pr >> 5);
            int sc = scol ^ ((r & 7) << 3);
            gload_lds16(A + (size_t)pr * lda + k0 + sc, &As[r * 64 + scol]);
        }
#pragma unroll
        for (int j = 0; j < 4; j++) {
            int r = srow + j * 32;
            int br = n0 + r; if (br > N - 1) br = N - 1;
            int sc = scol ^ ((r & 7) << 3);
            gload_lds16(Bm + (size_t)br * ldb + k0 + sc, &Bs[r * 64 + scol]);
        }
        __syncthreads();
#pragma unroll
        for (int kk = 0; kk < 64; kk += 32) {
            bf16x8 af[4], bfr[4];
#pragma unroll
            for (int i = 0; i < 4; i++) {
                int ar = wm + i * 16 + lane_r;
                af[i] = *(const bf16x8*)&As[ar * 64 + ((kk + lane_k) ^ ((ar & 7) << 3))];
            }
#pragma unroll
            for (int j = 0; j < 4; j++) {
                int br2 = wn + j * 16 + lane_r;
                bfr[j] = *(const bf16x8*)&Bs[br2 * 64 + ((kk + lane_k) ^ ((br2 & 7) << 3))];
            }
#pragma unroll
            for (int i = 0; i < 4; i++)
#pragma unroll
                for (int j = 0; j < 4; j++)
                    acc[i][j] = __builtin_amdgcn_mfma_f32_16x16x32_bf16(af[i], bfr[j], acc[i][j], 0, 0, 0);
        }
        __syncthreads();
    }

    int row_base = m0 + wm + ((l >> 4) << 2);
    int col_base = n0 + wn + lane_r;
#pragma unroll
    for (int j = 0; j < 4; j++) {
        int col = col_base + j * 16;
        if (col < N) {
            float bv = bias[col];
#pragma unroll
            for (int i = 0; i < 4; i++) {
#pragma unroll
                for (int r = 0; r < 4; r++) {
                    int row = row_base + i * 16 + r;
                    float v = acc[i][j][r] + bv;
                    if (zpack) {
                        int b = row >> 5, tt = row & 31;
                        size_t idx = (((size_t)(tt * 64 + (col >> 4)) * 4 + z) * 16
                                      + (col & 15)) * 64 + b;
                        ((ushort_t*)Cv)[idx] = f2bf(v);
                    } else if (f32out) {
                        ((float*)Cv)[(size_t)z * gsC + (size_t)row * ldc + col] = v;
                    } else {
                        ((ushort_t*)Cv)[(size_t)z * gsC + (size_t)row * ldc + col] = f2bf(v);
                    }
                }
            }
        }
    }
}

// hand-issued 16B load with literal offset into ring slot i (compiler cannot serialize)
#define GLD(i, o) asm volatile("global_load_dwordx4 %0, %1, off offset:" o \
                               : "=v"(ab[i]) : "v"(apx))
// One k-chunk: ds_reads BEFORE the counted wait; sched_barrier(0) is the ONLY verified
// fence vs MFMA hoisting past inline-asm waitcnt (rule #18). Keep register count EXACT
// (r11: extra live VGPRs -> spilled asm-output regs store garbage).
#define CHUNK(d, n, ISSUE)                                                                   \
    do {                                                                                     \
        const int kc2 = ((d) * 32 + lane_kb) * 2;                                            \
        bf16x8 b0 = *(const bf16x8*)((const char*)Ws + ((     lane_r) * 2048 + (kc2 ^ swz)));\
        bf16x8 b1 = *(const bf16x8*)((const char*)Ws + ((16 + lane_r) * 2048 + (kc2 ^ swz)));\
        bf16x8 b2 = *(const bf16x8*)((const char*)Ws + ((32 + lane_r) * 2048 + (kc2 ^ swz)));\
        bf16x8 b3 = *(const bf16x8*)((const char*)Ws + ((48 + lane_r) * 2048 + (kc2 ^ swz)));\
        asm volatile("s_waitcnt vmcnt(" n ")");                                              \
        __builtin_amdgcn_sched_barrier(0);                                                   \
        bf16x8 av = __builtin_bit_cast(bf16x8, ab[(d) & 15]);                                \
        acc[0] = __builtin_amdgcn_mfma_f32_16x16x32_bf16(av, b0, acc[0], 0, 0, 0);           \
        acc[1] = __builtin_amdgcn_mfma_f32_16x16x32_bf16(av, b1, acc[1], 0, 0, 0);           \
        acc[2] = __builtin_amdgcn_mfma_f32_16x16x32_bf16(av, b2, acc[2], 0, 0, 0);           \
        acc[3] = __builtin_amdgcn_mfma_f32_16x16x32_bf16(av, b3, acc[3], 0, 0, 0);           \
        ISSUE;                                                                               \
    } while (0)
// full 32-chunk K=1024 loop: prime 16-deep ring, consume with counted vmcnt, ring-refill
#define KLOOP32()                                                                            \
    int4 ab[16];                                                                             \
    GLD(0, "0");    GLD(1, "64");   GLD(2, "128");  GLD(3, "192");                           \
    GLD(4, "256");  GLD(5, "320");  GLD(6, "384");  GLD(7, "448");                           \
    GLD(8, "512");  GLD(9, "576");  GLD(10, "640"); GLD(11, "704");                          \
    GLD(12, "768"); GLD(13, "832"); GLD(14, "896"); GLD(15, "960");                          \
    CHUNK(0, "15", GLD(0, "1024"));  CHUNK(1, "15", GLD(1, "1088"));                         \
    CHUNK(2, "15", GLD(2, "1152"));  CHUNK(3, "15", GLD(3, "1216"));                         \
    CHUNK(4, "15", GLD(4, "1280"));  CHUNK(5, "15", GLD(5, "1344"));                         \
    CHUNK(6, "15", GLD(6, "1408"));  CHUNK(7, "15", GLD(7, "1472"));                         \
    CHUNK(8, "15", GLD(8, "1536"));  CHUNK(9, "15", GLD(9, "1600"));                         \
    CHUNK(10, "15", GLD(10, "1664")); CHUNK(11, "15", GLD(11, "1728"));                      \
    CHUNK(12, "15", GLD(12, "1792")); CHUNK(13, "15", GLD(13, "1856"));                      \
    CHUNK(14, "15", GLD(14, "1920")); CHUNK(15, "15", GLD(15, "1984"));                      \
    CHUNK(16, "15", (void)0); CHUNK(17, "14", (void)0);                                      \
    CHUNK(18, "13", (void)0); CHUNK(19, "12", (void)0);                                      \
    CHUNK(20, "11", (void)0); CHUNK(21, "10", (void)0);                                      \
    CHUNK(22, "9", (void)0);  CHUNK(23, "8", (void)0);                                       \
    CHUNK(24, "7", (void)0);  CHUNK(25, "6", (void)0);                                       \
    CHUNK(26, "5", (void)0);  CHUNK(27, "4", (void)0);                                       \
    CHUNK(28, "3", (void)0);  CHUNK(29, "2", (void)0);                                       \
    CHUNK(30, "1", (void)0);  CHUNK(31, "0", (void)0)

// ---------------- Stage E+F fused: persistent scan + streaming logits ----------------
// Blocks 0..63: validated scan. Block 0 additionally aggregates flags[t] -> done[t]
// (it polls flags[t] at step t+1 anyway). Blocks 64..220: consumer j converts its f32
// C_W panel inline (overlapped prologue), then per t polls the SINGLE done[t] dword
// (64x less poll traffic than r13's 64-dword gather) and computes 64 logits cols.
__launch_bounds__(256, 1)
__global__ void lstm_fused(const ushort_t* __restrict__ Wm,   // bf16 [4*1024][1024]
                           const float* __restrict__ Wb,      // f32 [4][1024]
                           const ushort_t* __restrict__ zb,   // packed g3 [t][cg][g][hc][b]
                           const ushort_t* __restrict__ h0b,  // bf16 [64][1024]
                           const float* __restrict__ c0,      // f32 [64][1024]
                           ushort_t* __restrict__ Hbt,        // bf16 [t][64][1024]
                           unsigned int* __restrict__ flags,  // [32][64] (+ done at +2048)
                           const float* __restrict__ CWf,     // f32 [10000][1024]
                           const float* __restrict__ Cb,      // f32 [10000]
                           float* __restrict__ out) {         // f32 [64][32][10000]
    __shared__ ushort_t Ws[64 * 1024];   // 128 KiB
    unsigned int* done = flags + 2048;   // [32] aggregated step flags
    int bid = blockIdx.x;
    int tid = threadIdx.x;
    int w = tid >> 6, l = tid & 63;
    int lane_r = l & 15, lane_kb = (l >> 4) << 3;

    if (bid < SCAN_BLOCKS) {
        // ================= SCAN ROLE (r12 body + done-aggregation by block 0) =========
        int cg = bid;
        for (int e = tid * 8; e < 65536; e += 2048) {
            int rowl = e >> 10, ke = e & 1023;
            int g = rowl >> 4, hc = rowl & 15;
            const ushort_t* src = Wm + ((size_t)(g * Hdim + cg * 16 + hc)) * Hdim + ke;
            int dstb = rowl * 2048 + ((ke * 2) ^ ((rowl & 7) << 4));
            *(int4*)((char*)Ws + dstb) = *(const int4*)src;
        }
        int hcol = cg * 16 + lane_r;
        float wbv[4];
#pragma unroll
        for (int g = 0; g < 4; g++) wbv[g] = Wb[g * Hdim + hcol];
        int rb0 = w * 16 + ((l >> 4) << 2);
        float cst[4];
#pragma unroll
        for (int r = 0; r < 4; r++) cst[r] = c0[(size_t)(rb0 + r) * Hdim + hcol];
        __syncthreads();

        int arow = w * 16 + lane_r;
        int swz = (lane_r & 7) << 4;

        for (int t = 0; t < Tdim; t++) {
            ushort_t g3s[4][4];
            size_t zbase = ((size_t)t * 64 + cg) * 4096 + (size_t)lane_r * 64 + rb0;
#pragma unroll
            for (int g = 0; g < 4; g++)
                *(ushort4*)g3s[g] = *(const ushort4*)(zb + zbase + (size_t)g * 1024);

            if (t > 0) {
                const unsigned int* fp = flags + (size_t)(t - 1) * 64 + l;
                unsigned int v;
                do {
                    v = __hip_atomic_load(fp, __ATOMIC_RELAXED, __HIP_MEMORY_SCOPE_AGENT);
                } while (__ballot(v != 0) != 0xFFFFFFFFFFFFFFFFull);
                if (cg == 0 && tid == 0) store_uint_wt(done + (t - 1), 1u);
            }
            __builtin_amdgcn_sched_barrier(0);

            const ushort_t* hp = t ? (Hbt + (size_t)(t - 1) * (Bdim * Hdim)) : h0b;
            const ushort_t* apx = hp + (size_t)arow * Hdim + lane_kb;

            f32x4 zero = {0.f, 0.f, 0.f, 0.f};
            f32x4 acc[4];
#pragma unroll
            for (int g = 0; g < 4; g++) acc[g] = zero;

            KLOOP32();

#pragma unroll
            for (int r = 0; r < 4; r++) {
                float zi = acc[0][r] + wbv[0] + bf2f(g3s[0][r]);
                float zf = acc[1][r] + wbv[1] + bf2f(g3s[1][r]);
                float zo = acc[2][r] + wbv[2] + bf2f(g3s[2][r]);
                float zc = acc[3][r] + wbv[3] + bf2f(g3s[3][r]);
                float it = __builtin_amdgcn_rcpf(1.f + __expf(-zi));
                float ft = __builtin_amdgcn_rcpf(1.f + __expf(-zf));
                float ot = __builtin_amdgcn_rcpf(1.f + __expf(-zo));
                float e2 = __expf(-2.f * zc);
                float ct = (1.f - e2) * __builtin_amdgcn_rcpf(1.f + e2);
                float cn = ft * cst[r] + it * ct;
                cst[r] = cn;
                store_short_wt(Hbt + (size_t)t * (Bdim * Hdim) + (size_t)(rb0 + r) * Hdim + hcol,
                               f2bf(ot * cn));
            }

            asm volatile("s_waitcnt vmcnt(0)" ::: "memory");
            __syncthreads();
            if (tid == 0) store_uint_wt(flags + (size_t)t * 64 + cg, 1u);
        }
        // publish the final aggregated flag
        if (cg == 0) {
            const unsigned int* fp = flags + (size_t)31 * 64 + l;
            unsigned int v;
            do {
                v = __hip_atomic_load(fp, __ATOMIC_RELAXED, __HIP_MEMORY_SCOPE_AGENT);
            } while (__ballot(v != 0) != 0xFFFFFFFFFFFFFFFFull);
            if (tid == 0) store_uint_wt(done + 31, 1u);
        }
    } else {
        // ================= CONSUMER ROLE: logits cols [j*64, j*64+64) =================
        int j = bid - SCAN_BLOCKS;
        // inline f32 -> bf16 conversion of this block's C_W panel (overlapped w/ scan)
        for (int e = tid * 8; e < 65536; e += 2048) {
            int rowl = e >> 10, ke = e & 1023;
            int n = j * 64 + rowl; if (n > Vdim - 1) n = Vdim - 1;
            const float* src = CWf + (size_t)n * Hdim + ke;
            float4 a = *(const float4*)(src);
            float4 b = *(const float4*)(src + 4);
            ushort_t o[8];
            o[0] = f2bf(a.x); o[1] = f2bf(a.y); o[2] = f2bf(a.z); o[3] = f2bf(a.w);
            o[4] = f2bf(b.x); o[5] = f2bf(b.y); o[6] = f2bf(b.z); o[7] = f2bf(b.w);
            int dstb = rowl * 2048 + ((ke * 2) ^ ((rowl & 7) << 4));
            *(int4*)((char*)Ws + dstb) = *(const int4*)o;
        }
        int rb0 = w * 16 + ((l >> 4) << 2);
        int arow = w * 16 + lane_r;
        int swz = (lane_r & 7) << 4;
        float cbv[4];
#pragma unroll
        for (int g = 0; g < 4; g++) {
            int col = j * 64 + g * 16 + lane_r;
            cbv[g] = Cb[col > Vdim - 1 ? Vdim - 1 : col];
        }
        __syncthreads();

        for (int t = 0; t < Tdim; t++) {
            // wave 0 polls the single aggregated done[t] dword
            if (w == 0) {
                const unsigned int* dp = done + t;
                unsigned int v;
                do {
                    __builtin_amdgcn_s_sleep(4);
                    v = __hip_atomic_load(dp, __ATOMIC_RELAXED, __HIP_MEMORY_SCOPE_AGENT);
                } while (v == 0);
            }
            __syncthreads();
            __builtin_amdgcn_sched_barrier(0);

            const ushort_t* apx = Hbt + (size_t)t * (Bdim * Hdim) + (size_t)arow * Hdim + lane_kb;

            f32x4 zero = {0.f, 0.f, 0.f, 0.f};
            f32x4 acc[4];
#pragma unroll
            for (int g = 0; g < 4; g++) acc[g] = zero;

            KLOOP32();

#pragma unroll
            for (int g = 0; g < 4; g++) {
                int col = j * 64 + g * 16 + lane_r;
                if (col < Vdim) {
#pragma unroll
                    for (int r = 0; r < 4; r++)
                        out[((size_t)(rb0 + r) * Tdim + t) * Vdim + col] = acc[g][r] + cbv[g];
                }
            }
        }
    }
}

extern "C" void kernel_launch(void* const* d_in, const int* in_sizes, int n_in,
                              void* d_out, int out_size, void* d_ws, size_t ws_size,
                              hipStream_t stream) {
    const int*   cap  = (const int*)d_in[0];
    const float* img  = (const float*)d_in[1];
    const float* Bemb = (const float*)d_in[2];
    const float* V_W  = (const float*)d_in[3];
    const float* V_b  = (const float*)d_in[4];
    const float* S_W  = (const float*)d_in[5];
    const float* S_b  = (const float*)d_in[6];
    const float* U_W  = (const float*)d_in[7];
    const float* U_b  = (const float*)d_in[8];
    const float* W_W  = (const float*)d_in[9];
    const float* W_b  = (const float*)d_in[10];
    const float* C_W  = (const float*)d_in[11];
    const float* C_b  = (const float*)d_in[12];
    const float* h0   = (const float*)d_in[13];
    const float* c0   = (const float*)d_in[14];

    char* ws = (char*)d_ws;
    int fused = ws_size >= (size_t)(64u) * 1024 * 1024;

    ushort_t* mir = (ushort_t*)(ws);                              // 35.66 MiB bf16 mirror
    ushort_t* X   = (ushort_t*)(ws + (size_t)(36u << 20));        // 2 MiB (dead after B)
    ushort_t* g1  = (ushort_t*)(ws + (size_t)(38u << 20));        // 8 MiB (dead after C)
    ushort_t *g2, *Hbt, *zbp; unsigned int* flags;
    if (fused) {
        // lifetime-overlapped layout (64 MiB): zb [36,52) over dead X+g1; g2 [52,60); Hbt [60,64)
        zbp   = (ushort_t*)(ws + (size_t)(36u << 20));
        g2    = (ushort_t*)(ws + (size_t)(52u << 20));
        Hbt   = (ushort_t*)(ws + (size_t)(60u << 20));
        flags = (unsigned int*)(ws + (size_t)(36u << 20) - 16384); // 16 KiB in mir tail gap
    } else {
        zbp   = (ushort_t*)d_out;
        g2    = (ushort_t*)(ws + (size_t)(46u << 20));
        Hbt   = (ushort_t*)(ws + (size_t)(54u << 20));
        flags = (unsigned int*)(ws + (size_t)(58u << 20));
    }

    const ushort_t* V_Wb = mir;
    const ushort_t* S_Wb = mir + 1048576L;
    const ushort_t* U_Wb = mir + 2097152L;
    const ushort_t* W_Wb = mir + 4194304L;
    const ushort_t* h0b  = mir + 8388608L;
    const ushort_t* C_Wb = mir + 8454144L;

    // fused: convert only V/S/U/W/h0 (4128 blocks); fallback: everything (9128)
    cvt_all<<<fused ? 4128 : 9128, 256, 0, stream>>>(V_W, S_W, U_W, W_W, h0, C_W, mir, flags);
    build_x<<<512, 256, 0, stream>>>(cap, img, Bemb, X);

    // Stage B: g1 = X (2048x512) * V_Wcat^T (2048x512) + V_b
    gemm_bt<<<dim3(16, 16, 1), 256, 0, stream>>>(X, 512, 0, V_Wb, 512, 0,
                                                 g1, 2048, 0, V_b, 0, 2048, 512, 0, 0, 0);
    // Stage C (per gate): g2[:, g] = g1[:, g] * S_W[g]^T + S_b[g]
    gemm_bt<<<dim3(4, 16, 4), 256, 0, stream>>>(g1, 2048, 512, S_Wb, 512, 512 * 512,
                                                g2, 2048, 512, S_b, 512, 512, 512, 0, 0, 0);
    // Stage D (per gate): zb(packed) = g2[:, g] * U_W[g]^T + U_b[g]
    gemm_bt<<<dim3(8, 16, 4), 256, 0, stream>>>(g2, 2048, 512, U_Wb, 512, 1024 * 512,
                                                zbp, 0, 0, U_b, 1024, 1024, 512, 0, 1, 0);
    // Stage E(+F if fused): cooperative launch
    {
        const ushort_t* a0 = W_Wb; const float* a1 = W_b; const ushort_t* a2 = zbp;
        const ushort_t* a3 = h0b;  const float* a4 = c0;  ushort_t* a5 = Hbt;
        unsigned int* a6 = flags;  const float* a7 = C_W; const float* a8 = C_b;
        float* a9 = (float*)d_out;
        void* sargs[10] = {(void*)&a0, (void*)&a1, (void*)&a2, (void*)&a3, (void*)&a4,
                           (void*)&a5, (void*)&a6, (void*)&a7, (void*)&a8, (void*)&a9};
        int grid = fused ? (SCAN_BLOCKS + CONS_BLOCKS) : SCAN_BLOCKS;
        hipLaunchCooperativeKernel((const void*)lstm_fused, dim3(grid), dim3(256),
                                   sargs, 0, stream);
    }
    if (!fused) {
        // Stage F fallback: out = Hbt([t][b][h], aswap) * C_W^T + C_b (f32 out)
        gemm_bt<<<dim3(79, 16, 1), 256, 0, stream>>>(Hbt, 1024, 0, C_Wb, 1024, 0,
                                                     d_out, 10000, 0, C_b, 0,
                                                     10000, 1024, 1, 0, 1);
    }
}

// Round 16
// 327.605 us; speedup vs baseline: 1.6649x; 1.0139x over previous
//
#include <hip/hip_runtime.h>
#include <hip/hip_bf16.h>

typedef __attribute__((ext_vector_type(8))) __bf16 bf16x8;
typedef __attribute__((ext_vector_type(4))) float f32x4;
typedef unsigned short ushort_t;

#define Bdim 64
#define Tdim 32
#define Edim 512
#define Fdim 512
#define Hdim 1024
#define Vdim 10000
#define SCAN_BLOCKS 64
#define CONS_BLOCKS 157   // ceil(10000/64) consumer blocks for fused logits

__device__ __forceinline__ float bf2f(ushort_t u) {
    unsigned int x = ((unsigned int)u) << 16;
    union { unsigned int i; float f; } c; c.i = x; return c.f;
}
__device__ __forceinline__ ushort_t f2bf(float f) {
    __hip_bfloat16 h = __float2bfloat16(f);
    union { __hip_bfloat16 h; ushort_t u; } c; c.h = h; return c.u;
}

__device__ __forceinline__ void gload_lds16(const void* g, void* l) {
    __builtin_amdgcn_global_load_lds(
        (const __attribute__((address_space(1))) unsigned int*)g,
        (__attribute__((address_space(3))) unsigned int*)l, 16, 0, 0);
}

// write-through stores: visible device-wide once vmcnt-complete, no dirty local-L2 line
__device__ __forceinline__ void store_short_wt(ushort_t* p, ushort_t v) {
    asm volatile("global_store_short %0, %1, off sc0 sc1"
                 : : "v"(p), "v"((unsigned int)v) : "memory");
}
__device__ __forceinline__ void store_uint_wt(unsigned int* p, unsigned int v) {
    asm volatile("global_store_dword %0, %1, off sc0 sc1"
                 : : "v"(p), "v"(v) : "memory");
}

// ---------------- Stage 0+A merged: f32 -> bf16 mirror, zero flags, build X ----------------
// blocks [0, ncvt): convert V/S/U/W/h0 (+C_W in fallback); blocks [ncvt, ncvt+512): build X.
__global__ void cvt_build(const float* __restrict__ vw, const float* __restrict__ sw,
                          const float* __restrict__ uw, const float* __restrict__ ww,
                          const float* __restrict__ h0, const float* __restrict__ cw,
                          ushort_t* __restrict__ mir, unsigned int* __restrict__ flg,
                          const int* __restrict__ cap, const float* __restrict__ img,
                          const float* __restrict__ emb, ushort_t* __restrict__ X,
                          int ncvt) {
    if (blockIdx.x >= (unsigned)ncvt) {
        // ---- build_x role ----
        int idx = (blockIdx.x - ncvt) * blockDim.x + threadIdx.x;
        int row = idx >> 6;
        int c8  = (idx & 63) << 3;
        int b = row >> 5, t = row & 31;
        const float* src = (t == 0) ? (img + (size_t)b * Edim)
                                    : (emb + (size_t)cap[b * Tdim + (t - 1)] * Edim);
        float4 a  = *(const float4*)(src + c8);
        float4 bb = *(const float4*)(src + c8 + 4);
        ushort_t o[8];
        o[0] = f2bf(a.x);  o[1] = f2bf(a.y);  o[2] = f2bf(a.z);  o[3] = f2bf(a.w);
        o[4] = f2bf(bb.x); o[5] = f2bf(bb.y); o[6] = f2bf(bb.z); o[7] = f2bf(bb.w);
        *(int4*)(X + (size_t)row * Edim + c8) = *(const int4*)o;
        return;
    }
    if (blockIdx.x == 0) {   // zero 16 KiB flags[32][64] + done[32] region
        int4 zz = {0, 0, 0, 0};
#pragma unroll
        for (int q = 0; q < 4; q++) ((int4*)flg)[threadIdx.x * 4 + q] = zz;
    }
    long idx = ((long)blockIdx.x * blockDim.x + threadIdx.x) * 8;
    const float* src; long off;
    if      (idx <  1048576L) { src = vw; off = idx; }
    else if (idx <  2097152L) { src = sw; off = idx - 1048576L; }
    else if (idx <  4194304L) { src = uw; off = idx - 2097152L; }
    else if (idx <  8388608L) { src = ww; off = idx - 4194304L; }
    else if (idx <  8454144L) { src = h0; off = idx - 8388608L; }
    else if (idx < 18694144L) { src = cw; off = idx - 8454144L; }
    else return;
    float4 a = *(const float4*)(src + off);
    float4 b = *(const float4*)(src + off + 4);
    ushort_t o[8];
    o[0] = f2bf(a.x); o[1] = f2bf(a.y); o[2] = f2bf(a.z); o[3] = f2bf(a.w);
    o[4] = f2bf(b.x); o[5] = f2bf(b.y); o[6] = f2bf(b.z); o[7] = f2bf(b.w);
    *(int4*)(mir + idx) = *(const int4*)o;
}

// ---------------- Generic GEMM: C[m][n] = sum_k A[m][k]*Bt[n][k] + bias[n] ----------------
__launch_bounds__(256)
__global__ void gemm_bt(const ushort_t* __restrict__ A, long lda, long gsA,
                        const ushort_t* __restrict__ Bm, long ldb, long gsB,
                        void* __restrict__ Cv, long ldc, long gsC,
                        const float* __restrict__ bias, long gsBias,
                        int N, int K, int f32out, int zpack, int aswap) {
    __shared__ ushort_t As[128 * 64];
    __shared__ ushort_t Bs[128 * 64];
    int z = blockIdx.z;
    A += (size_t)z * gsA; Bm += (size_t)z * gsB; bias += (size_t)z * gsBias;

    int nx = gridDim.x, ny = gridDim.y;
    int lin = blockIdx.x + nx * blockIdx.y;
    int per_xcd = (nx * ny) >> 3;
    int l2 = (lin & 7) * per_xcd + (lin >> 3);
    int bx = l2 / ny, by = l2 % ny;

    int tid = threadIdx.x;
    int w = tid >> 6, l = tid & 63;
    int wm = (w >> 1) * 64, wn = (w & 1) * 64;
    int m0 = by * 128, n0 = bx * 128;

    int srow = tid >> 3;
    int scol = (tid & 7) << 3;

    int lane_r = l & 15;
    int lane_k = (l >> 4) << 3;

    f32x4 zero = {0.f, 0.f, 0.f, 0.f};
    f32x4 acc[4][4];
#pragma unroll
    for (int i = 0; i < 4; i++)
#pragma unroll
        for (int j = 0; j < 4; j++) acc[i][j] = zero;

    for (int k0 = 0; k0 < K; k0 += 64) {
#pragma unroll
        for (int j = 0; j < 4; j++) {
            int r = srow + j * 32;
            int pr = m0 + r;
            if (aswap) pr = ((pr & 31) << 6) + (pr >> 5);
            int sc = scol ^ ((r & 7) << 3);
            gload_lds16(A + (size_t)pr * lda + k0 + sc, &As[r * 64 + scol]);
        }
#pragma unroll
        for (int j = 0; j < 4; j++) {
            int r = srow + j * 32;
            int br = n0 + r; if (br > N - 1) br = N - 1;
            int sc = scol ^ ((r & 7) << 3);
            gload_lds16(Bm + (size_t)br * ldb + k0 + sc, &Bs[r * 64 + scol]);
        }
        __syncthreads();
#pragma unroll
        for (int kk = 0; kk < 64; kk += 32) {
            bf16x8 af[4], bfr[4];
#pragma unroll
            for (int i = 0; i < 4; i++) {
                int ar = wm + i * 16 + lane_r;
                af[i] = *(const bf16x8*)&As[ar * 64 + ((kk + lane_k) ^ ((ar & 7) << 3))];
            }
#pragma unroll
            for (int j = 0; j < 4; j++) {
                int br2 = wn + j * 16 + lane_r;
                bfr[j] = *(const bf16x8*)&Bs[br2 * 64 + ((kk + lane_k) ^ ((br2 & 7) << 3))];
            }
#pragma unroll
            for (int i = 0; i < 4; i++)
#pragma unroll
                for (int j = 0; j < 4; j++)
                    acc[i][j] = __builtin_amdgcn_mfma_f32_16x16x32_bf16(af[i], bfr[j], acc[i][j], 0, 0, 0);
        }
        __syncthreads();
    }

    int row_base = m0 + wm + ((l >> 4) << 2);
    int col_base = n0 + wn + lane_r;
#pragma unroll
    for (int j = 0; j < 4; j++) {
        int col = col_base + j * 16;
        if (col < N) {
            float bv = bias[col];
#pragma unroll
            for (int i = 0; i < 4; i++) {
#pragma unroll
                for (int r = 0; r < 4; r++) {
                    int row = row_base + i * 16 + r;
                    float v = acc[i][j][r] + bv;
                    if (zpack) {
                        int b = row >> 5, tt = row & 31;
                        size_t idx = (((size_t)(tt * 64 + (col >> 4)) * 4 + z) * 16
                                      + (col & 15)) * 64 + b;
                        ((ushort_t*)Cv)[idx] = f2bf(v);
                    } else if (f32out) {
                        ((float*)Cv)[(size_t)z * gsC + (size_t)row * ldc + col] = v;
                    } else {
                        ((ushort_t*)Cv)[(size_t)z * gsC + (size_t)row * ldc + col] = f2bf(v);
                    }
                }
            }
        }
    }
}

// hand-issued 16B load with literal offset into ring slot i (compiler cannot serialize)
#define GLD(i, o) asm volatile("global_load_dwordx4 %0, %1, off offset:" o \
                               : "=v"(ab[i]) : "v"(apx))
// One k-chunk: ds_reads BEFORE the counted wait; sched_barrier(0) is the ONLY verified
// fence vs MFMA hoisting past inline-asm waitcnt (rule #18). Keep register count EXACT
// (r11/r15: extra live VGPRs in this loop break the kernel; structure is frozen).
#define CHUNK(d, n, ISSUE)                                                                   \
    do {                                                                                     \
        const int kc2 = ((d) * 32 + lane_kb) * 2;                                            \
        bf16x8 b0 = *(const bf16x8*)((const char*)Ws + ((     lane_r) * 2048 + (kc2 ^ swz)));\
        bf16x8 b1 = *(const bf16x8*)((const char*)Ws + ((16 + lane_r) * 2048 + (kc2 ^ swz)));\
        bf16x8 b2 = *(const bf16x8*)((const char*)Ws + ((32 + lane_r) * 2048 + (kc2 ^ swz)));\
        bf16x8 b3 = *(const bf16x8*)((const char*)Ws + ((48 + lane_r) * 2048 + (kc2 ^ swz)));\
        asm volatile("s_waitcnt vmcnt(" n ")");                                              \
        __builtin_amdgcn_sched_barrier(0);                                                   \
        bf16x8 av = __builtin_bit_cast(bf16x8, ab[(d) & 15]);                                \
        acc[0] = __builtin_amdgcn_mfma_f32_16x16x32_bf16(av, b0, acc[0], 0, 0, 0);           \
        acc[1] = __builtin_amdgcn_mfma_f32_16x16x32_bf16(av, b1, acc[1], 0, 0, 0);           \
        acc[2] = __builtin_amdgcn_mfma_f32_16x16x32_bf16(av, b2, acc[2], 0, 0, 0);           \
        acc[3] = __builtin_amdgcn_mfma_f32_16x16x32_bf16(av, b3, acc[3], 0, 0, 0);           \
        ISSUE;                                                                               \
    } while (0)
// full 32-chunk K=1024 loop: prime 16-deep ring, consume with counted vmcnt, ring-refill
#define KLOOP32()                                                                            \
    int4 ab[16];                                                                             \
    GLD(0, "0");    GLD(1, "64");   GLD(2, "128");  GLD(3, "192");                           \
    GLD(4, "256");  GLD(5, "320");  GLD(6, "384");  GLD(7, "448");                           \
    GLD(8, "512");  GLD(9, "576");  GLD(10, "640"); GLD(11, "704");                          \
    GLD(12, "768"); GLD(13, "832"); GLD(14, "896"); GLD(15, "960");                          \
    CHUNK(0, "15", GLD(0, "1024"));  CHUNK(1, "15", GLD(1, "1088"));                         \
    CHUNK(2, "15", GLD(2, "1152"));  CHUNK(3, "15", GLD(3, "1216"));                         \
    CHUNK(4, "15", GLD(4, "1280"));  CHUNK(5, "15", GLD(5, "1344"));                         \
    CHUNK(6, "15", GLD(6, "1408"));  CHUNK(7, "15", GLD(7, "1472"));                         \
    CHUNK(8, "15", GLD(8, "1536"));  CHUNK(9, "15", GLD(9, "1600"));                         \
    CHUNK(10, "15", GLD(10, "1664")); CHUNK(11, "15", GLD(11, "1728"));                      \
    CHUNK(12, "15", GLD(12, "1792")); CHUNK(13, "15", GLD(13, "1856"));                      \
    CHUNK(14, "15", GLD(14, "1920")); CHUNK(15, "15", GLD(15, "1984"));                      \
    CHUNK(16, "15", (void)0); CHUNK(17, "14", (void)0);                                      \
    CHUNK(18, "13", (void)0); CHUNK(19, "12", (void)0);                                      \
    CHUNK(20, "11", (void)0); CHUNK(21, "10", (void)0);                                      \
    CHUNK(22, "9", (void)0);  CHUNK(23, "8", (void)0);                                       \
    CHUNK(24, "7", (void)0);  CHUNK(25, "6", (void)0);                                       \
    CHUNK(26, "5", (void)0);  CHUNK(27, "4", (void)0);                                       \
    CHUNK(28, "3", (void)0);  CHUNK(29, "2", (void)0);                                       \
    CHUNK(30, "1", (void)0);  CHUNK(31, "0", (void)0)

// ---------------- Stage E+F fused: persistent scan + streaming logits (r14, frozen) -------
__launch_bounds__(256, 1)
__global__ void lstm_fused(const ushort_t* __restrict__ Wm,   // bf16 [4*1024][1024]
                           const float* __restrict__ Wb,      // f32 [4][1024]
                           const ushort_t* __restrict__ zb,   // packed g3 [t][cg][g][hc][b]
                           const ushort_t* __restrict__ h0b,  // bf16 [64][1024]
                           const float* __restrict__ c0,      // f32 [64][1024]
                           ushort_t* __restrict__ Hbt,        // bf16 [t][64][1024]
                           unsigned int* __restrict__ flags,  // [32][64] (+ done at +2048)
                           const float* __restrict__ CWf,     // f32 [10000][1024]
                           const float* __restrict__ Cb,      // f32 [10000]
                           float* __restrict__ out) {         // f32 [64][32][10000]
    __shared__ ushort_t Ws[64 * 1024];   // 128 KiB
    unsigned int* done = flags + 2048;   // [32] aggregated step flags
    int bid = blockIdx.x;
    int tid = threadIdx.x;
    int w = tid >> 6, l = tid & 63;
    int lane_r = l & 15, lane_kb = (l >> 4) << 3;

    if (bid < SCAN_BLOCKS) {
        // ================= SCAN ROLE (r12 body + done-aggregation by block 0) =========
        int cg = bid;
        for (int e = tid * 8; e < 65536; e += 2048) {
            int rowl = e >> 10, ke = e & 1023;
            int g = rowl >> 4, hc = rowl & 15;
            const ushort_t* src = Wm + ((size_t)(g * Hdim + cg * 16 + hc)) * Hdim + ke;
            int dstb = rowl * 2048 + ((ke * 2) ^ ((rowl & 7) << 4));
            *(int4*)((char*)Ws + dstb) = *(const int4*)src;
        }
        int hcol = cg * 16 + lane_r;
        float wbv[4];
#pragma unroll
        for (int g = 0; g < 4; g++) wbv[g] = Wb[g * Hdim + hcol];
        int rb0 = w * 16 + ((l >> 4) << 2);
        float cst[4];
#pragma unroll
        for (int r = 0; r < 4; r++) cst[r] = c0[(size_t)(rb0 + r) * Hdim + hcol];
        __syncthreads();

        int arow = w * 16 + lane_r;
        int swz = (lane_r & 7) << 4;

        for (int t = 0; t < Tdim; t++) {
            ushort_t g3s[4][4];
            size_t zbase = ((size_t)t * 64 + cg) * 4096 + (size_t)lane_r * 64 + rb0;
#pragma unroll
            for (int g = 0; g < 4; g++)
                *(ushort4*)g3s[g] = *(const ushort4*)(zb + zbase + (size_t)g * 1024);

            if (t > 0) {
                const unsigned int* fp = flags + (size_t)(t - 1) * 64 + l;
                unsigned int v;
                do {
                    v = __hip_atomic_load(fp, __ATOMIC_RELAXED, __HIP_MEMORY_SCOPE_AGENT);
                } while (__ballot(v != 0) != 0xFFFFFFFFFFFFFFFFull);
                if (cg == 0 && tid == 0) store_uint_wt(done + (t - 1), 1u);
            }
            __builtin_amdgcn_sched_barrier(0);

            const ushort_t* hp = t ? (Hbt + (size_t)(t - 1) * (Bdim * Hdim)) : h0b;
            const ushort_t* apx = hp + (size_t)arow * Hdim + lane_kb;

            f32x4 zero = {0.f, 0.f, 0.f, 0.f};
            f32x4 acc[4];
#pragma unroll
            for (int g = 0; g < 4; g++) acc[g] = zero;

            KLOOP32();

#pragma unroll
            for (int r = 0; r < 4; r++) {
                float zi = acc[0][r] + wbv[0] + bf2f(g3s[0][r]);
                float zf = acc[1][r] + wbv[1] + bf2f(g3s[1][r]);
                float zo = acc[2][r] + wbv[2] + bf2f(g3s[2][r]);
                float zc = acc[3][r] + wbv[3] + bf2f(g3s[3][r]);
                float it = __builtin_amdgcn_rcpf(1.f + __expf(-zi));
                float ft = __builtin_amdgcn_rcpf(1.f + __expf(-zf));
                float ot = __builtin_amdgcn_rcpf(1.f + __expf(-zo));
                float e2 = __expf(-2.f * zc);
                float ct = (1.f - e2) * __builtin_amdgcn_rcpf(1.f + e2);
                float cn = ft * cst[r] + it * ct;
                cst[r] = cn;
                store_short_wt(Hbt + (size_t)t * (Bdim * Hdim) + (size_t)(rb0 + r) * Hdim + hcol,
                               f2bf(ot * cn));
            }

            asm volatile("s_waitcnt vmcnt(0)" ::: "memory");
            __syncthreads();
            if (tid == 0) store_uint_wt(flags + (size_t)t * 64 + cg, 1u);
        }
        // publish the final aggregated flag
        if (cg == 0) {
            const unsigned int* fp = flags + (size_t)31 * 64 + l;
            unsigned int v;
            do {
                v = __hip_atomic_load(fp, __ATOMIC_RELAXED, __HIP_MEMORY_SCOPE_AGENT);
            } while (__ballot(v != 0) != 0xFFFFFFFFFFFFFFFFull);
            if (tid == 0) store_uint_wt(done + 31, 1u);
        }
    } else {
        // ================= CONSUMER ROLE: logits cols [j*64, j*64+64) =================
        int j = bid - SCAN_BLOCKS;
        // inline f32 -> bf16 conversion of this block's C_W panel (overlapped w/ scan)
        for (int e = tid * 8; e < 65536; e += 2048) {
            int rowl = e >> 10, ke = e & 1023;
            int n = j * 64 + rowl; if (n > Vdim - 1) n = Vdim - 1;
            const float* src = CWf + (size_t)n * Hdim + ke;
            float4 a = *(const float4*)(src);
            float4 b = *(const float4*)(src + 4);
            ushort_t o[8];
            o[0] = f2bf(a.x); o[1] = f2bf(a.y); o[2] = f2bf(a.z); o[3] = f2bf(a.w);
            o[4] = f2bf(b.x); o[5] = f2bf(b.y); o[6] = f2bf(b.z); o[7] = f2bf(b.w);
            int dstb = rowl * 2048 + ((ke * 2) ^ ((rowl & 7) << 4));
            *(int4*)((char*)Ws + dstb) = *(const int4*)o;
        }
        int rb0 = w * 16 + ((l >> 4) << 2);
        int arow = w * 16 + lane_r;
        int swz = (lane_r & 7) << 4;
        float cbv[4];
#pragma unroll
        for (int g = 0; g < 4; g++) {
            int col = j * 64 + g * 16 + lane_r;
            cbv[g] = Cb[col > Vdim - 1 ? Vdim - 1 : col];
        }
        __syncthreads();

        for (int t = 0; t < Tdim; t++) {
            // wave 0 polls the single aggregated done[t] dword
            if (w == 0) {
                const unsigned int* dp = done + t;
                unsigned int v;
                do {
                    __builtin_amdgcn_s_sleep(4);
                    v = __hip_atomic_load(dp, __ATOMIC_RELAXED, __HIP_MEMORY_SCOPE_AGENT);
                } while (v == 0);
            }
            __syncthreads();
            __builtin_amdgcn_sched_barrier(0);

            const ushort_t* apx = Hbt + (size_t)t * (Bdim * Hdim) + (size_t)arow * Hdim + lane_kb;

            f32x4 zero = {0.f, 0.f, 0.f, 0.f};
            f32x4 acc[4];
#pragma unroll
            for (int g = 0; g < 4; g++) acc[g] = zero;

            KLOOP32();

#pragma unroll
            for (int g = 0; g < 4; g++) {
                int col = j * 64 + g * 16 + lane_r;
                if (col < Vdim) {
#pragma unroll
                    for (int r = 0; r < 4; r++)
                        out[((size_t)(rb0 + r) * Tdim + t) * Vdim + col] = acc[g][r] + cbv[g];
                }
            }
        }
    }
}

extern "C" void kernel_launch(void* const* d_in, const int* in_sizes, int n_in,
                              void* d_out, int out_size, void* d_ws, size_t ws_size,
                              hipStream_t stream) {
    const int*   cap  = (const int*)d_in[0];
    const float* img  = (const float*)d_in[1];
    const float* Bemb = (const float*)d_in[2];
    const float* V_W  = (const float*)d_in[3];
    const float* V_b  = (const float*)d_in[4];
    const float* S_W  = (const float*)d_in[5];
    const float* S_b  = (const float*)d_in[6];
    const float* U_W  = (const float*)d_in[7];
    const float* U_b  = (const float*)d_in[8];
    const float* W_W  = (const float*)d_in[9];
    const float* W_b  = (const float*)d_in[10];
    const float* C_W  = (const float*)d_in[11];
    const float* C_b  = (const float*)d_in[12];
    const float* h0   = (const float*)d_in[13];
    const float* c0   = (const float*)d_in[14];

    char* ws = (char*)d_ws;
    int fused = ws_size >= (size_t)(64u) * 1024 * 1024;

    ushort_t* mir = (ushort_t*)(ws);                              // 35.66 MiB bf16 mirror
    ushort_t* X   = (ushort_t*)(ws + (size_t)(36u << 20));        // 2 MiB (dead after B)
    ushort_t* g1  = (ushort_t*)(ws + (size_t)(38u << 20));        // 8 MiB (dead after C)
    ushort_t *g2, *Hbt, *zbp; unsigned int* flags;
    if (fused) {
        // lifetime-overlapped layout (64 MiB): zb [36,52) over dead X+g1; g2 [52,60); Hbt [60,64)
        zbp   = (ushort_t*)(ws + (size_t)(36u << 20));
        g2    = (ushort_t*)(ws + (size_t)(52u << 20));
        Hbt   = (ushort_t*)(ws + (size_t)(60u << 20));
        flags = (unsigned int*)(ws + (size_t)(36u << 20) - 16384); // 16 KiB in mir tail gap
    } else {
        zbp   = (ushort_t*)d_out;
        g2    = (ushort_t*)(ws + (size_t)(46u << 20));
        Hbt   = (ushort_t*)(ws + (size_t)(54u << 20));
        flags = (unsigned int*)(ws + (size_t)(58u << 20));
    }

    const ushort_t* V_Wb = mir;
    const ushort_t* S_Wb = mir + 1048576L;
    const ushort_t* U_Wb = mir + 2097152L;
    const ushort_t* W_Wb = mir + 4194304L;
    const ushort_t* h0b  = mir + 8388608L;
    const ushort_t* C_Wb = mir + 8454144L;

    // merged stage 0+A: cvt blocks + 512 build_x blocks in one dispatch
    int ncvt = fused ? 4128 : 9128;
    cvt_build<<<ncvt + 512, 256, 0, stream>>>(V_W, S_W, U_W, W_W, h0, C_W, mir, flags,
                                              cap, img, Bemb, X, ncvt);

    // Stage B: g1 = X (2048x512) * V_Wcat^T (2048x512) + V_b
    gemm_bt<<<dim3(16, 16, 1), 256, 0, stream>>>(X, 512, 0, V_Wb, 512, 0,
                                                 g1, 2048, 0, V_b, 0, 2048, 512, 0, 0, 0);
    // Stage C (per gate): g2[:, g] = g1[:, g] * S_W[g]^T + S_b[g]
    gemm_bt<<<dim3(4, 16, 4), 256, 0, stream>>>(g1, 2048, 512, S_Wb, 512, 512 * 512,
                                                g2, 2048, 512, S_b, 512, 512, 512, 0, 0, 0);
    // Stage D (per gate): zb(packed) = g2[:, g] * U_W[g]^T + U_b[g]
    gemm_bt<<<dim3(8, 16, 4), 256, 0, stream>>>(g2, 2048, 512, U_Wb, 512, 1024 * 512,
                                                zbp, 0, 0, U_b, 1024, 1024, 512, 0, 1, 0);
    // Stage E(+F if fused): cooperative launch
    {
        const ushort_t* a0 = W_Wb; const float* a1 = W_b; const ushort_t* a2 = zbp;
        const ushort_t* a3 = h0b;  const float* a4 = c0;  ushort_t* a5 = Hbt;
        unsigned int* a6 = flags;  const float* a7 = C_W; const float* a8 = C_b;
        float* a9 = (float*)d_out;
        void* sargs[10] = {(void*)&a0, (void*)&a1, (void*)&a2, (void*)&a3, (void*)&a4,
                           (void*)&a5, (void*)&a6, (void*)&a7, (void*)&a8, (void*)&a9};
        int grid = fused ? (SCAN_BLOCKS + CONS_BLOCKS) : SCAN_BLOCKS;
        hipLaunchCooperativeKernel((const void*)lstm_fused, dim3(grid), dim3(256),
                                   sargs, 0, stream);
    }
    if (!fused) {
        // Stage F fallback: out = Hbt([t][b][h], aswap) * C_W^T + C_b (f32 out)
        gemm_bt<<<dim3(79, 16, 1), 256, 0, stream>>>(Hbt, 1024, 0, C_Wb, 1024, 0,
                                                     d_out, 10000, 0, C_b, 0,
                                                     10000, 1024, 1, 0, 1);
    }
}